// Round 15
// baseline (169.959 us; speedup 1.0000x reference)
//
#include <hip/hip_runtime.h>
#include <hip/hip_bf16.h>

// B=4, S=1024, D=1024, H=16, DH=64. Softmax over HEADS (per (i,j)), per reference.

using f32x4  = __attribute__((ext_vector_type(4))) float;
using f32x2  = __attribute__((ext_vector_type(2))) float;
using bf16x8 = __attribute__((ext_vector_type(8))) short;
using bf16x4 = __attribute__((ext_vector_type(4))) short;

__device__ inline unsigned short f2b(float f){
    unsigned u = __float_as_uint(f);
    unsigned r = (u + 0x7fffu + ((u >> 16) & 1u)) >> 16;
    return (unsigned short)r;
}
__device__ inline float b2f(unsigned short s){
    return __uint_as_float(((unsigned)s) << 16);
}

#define GLL16(gp, lp) __builtin_amdgcn_global_load_lds( \
    (const __attribute__((address_space(1))) void*)(gp), \
    (__attribute__((address_space(3))) void*)(lp), 16, 0, 0)

#define LGKM0 do { asm volatile("s_waitcnt lgkmcnt(0)" ::: "memory"); \
                   __builtin_amdgcn_sched_barrier(0); } while(0)
#define BAR   do { __builtin_amdgcn_s_barrier(); \
                   __builtin_amdgcn_sched_barrier(0); } while(0)

// ---------------- convert q,k,v f32 -> bf16, contiguous [3][4096][1024] -------
__global__ __launch_bounds__(256) void convert_qkv(
    const float* __restrict__ q, const float* __restrict__ k, const float* __restrict__ v,
    unsigned short* __restrict__ dst)
{
    const long gid = (long)blockIdx.x * 256 + threadIdx.x;
    const int  t   = (int)(gid >> 20);
    const long off = (gid & 1048575) << 2;
    const float* src = (t == 0) ? q : (t == 1) ? k : v;
    const float4 x = *(const float4*)(src + off);
    ushort4 o;
    o.x = f2b(x.x); o.y = f2b(x.y); o.z = f2b(x.z); o.w = f2b(x.w);
    *(ushort4*)(dst + (long)t * 4194304 + off) = o;
}

// ---------------- transpose+convert W f32 [k][n] -> bf16 [n][k] ---------------
__global__ __launch_bounds__(256) void wtrans(
    const float* __restrict__ w0, const float* __restrict__ w1,
    const float* __restrict__ w2, const float* __restrict__ w3,
    unsigned short* __restrict__ out)
{
    const float* W = (blockIdx.z == 0) ? w0 : (blockIdx.z == 1) ? w1 : (blockIdx.z == 2) ? w2 : w3;
    unsigned short* O = out + (long)blockIdx.z * 1048576;
    __shared__ float t[32][33];
    const int n0 = blockIdx.x * 32, k0 = blockIdx.y * 32;
    const int tx = threadIdx.x, ty = threadIdx.y;
    #pragma unroll
    for (int i = 0; i < 4; i++)
        t[ty + 8*i][tx] = W[(long)(k0 + ty + 8*i) * 1024 + n0 + tx];
    __syncthreads();
    #pragma unroll
    for (int i = 0; i < 4; i++)
        O[(long)(n0 + ty + 8*i) * 1024 + k0 + tx] = f2b(t[tx][ty + 8*i]);
}

// ---------------- K -> MFMA fragment layout -----------------------------------
// Kf[b][jt(64)][hk(32=h*2+ks)][lane(64)][e(8)]:
//   Kf(...) = Km[b][jt*16 + (l&15)][ (hk>>1)*64 + (hk&1)*32 + (l>>4)*8 + e ]
__global__ __launch_bounds__(256) void kf_trans(
    const unsigned short* __restrict__ Km, unsigned short* __restrict__ Kf)
{
    const int b = blockIdx.y, jt = blockIdx.x;
    __shared__ unsigned short t[16][1032];
    const int tid = threadIdx.x;
    #pragma unroll
    for (int p = 0; p < 8; p++) {
        const int idx = p * 2048 + tid * 8;
        const int r = idx >> 10, c = idx & 1023;
        *(uint4*)&t[r][c] = *(const uint4*)(Km + (long)(b*1024 + jt*16 + r) * 1024 + c);
    }
    __syncthreads();
    #pragma unroll
    for (int p = 0; p < 8; p++) {
        const int o  = p * 2048 + tid * 8;
        const int hk = o >> 9;
        const int l  = (o >> 3) & 63;
        const int cc = (hk >> 1) * 64 + (hk & 1) * 32 + (l >> 4) * 8;
        *(uint4*)(Kf + (long)(b*64 + jt) * 16384 + o) = *(const uint4*)&t[l & 15][cc];
    }
}

// ---------------- V -> MFMA fragment layout -----------------------------------
// Vf[b][jg(32)][hn(64=h*4+n)][lane(64)][e(8)]:
//   Vf(...) = Vm[b][jg*32 + (l>>4)*8 + e][ (hn>>2)*64 + (hn&3)*16 + (l&15) ]
__global__ __launch_bounds__(256) void vf_trans(
    const unsigned short* __restrict__ Vm, unsigned short* __restrict__ Vf)
{
    const int b = blockIdx.y, jg = blockIdx.x;
    __shared__ unsigned short t[32][1032];
    const int tid = threadIdx.x;
    #pragma unroll
    for (int p = 0; p < 16; p++) {
        const int idx = p * 2048 + tid * 8;
        const int r = idx >> 10, c = idx & 1023;
        *(uint4*)&t[r][c] = *(const uint4*)(Vm + (long)(b*1024 + jg*32 + r) * 1024 + c);
    }
    __syncthreads();
    #pragma unroll
    for (int p = 0; p < 16; p++) {
        const int o  = p * 2048 + tid * 8;
        const int hn = o >> 9;
        const int l  = (o >> 3) & 63;
        const int col = (hn >> 2) * 64 + (hn & 3) * 16 + (l & 15);
        const int r0  = (l >> 4) * 8;
        unsigned short vv[8];
        #pragma unroll
        for (int e = 0; e < 8; e++) vv[e] = t[r0 + e][col];
        *(uint4*)(Vf + (long)(b*32 + jg) * 32768 + o) = *(const uint4*)vv;
    }
}

// ---------------- GEMM tile body (m97 structure) ------------------------------
template<int OUTF32>
__device__ __forceinline__ void gemm_body(
    const unsigned short* __restrict__ A,
    const unsigned short* __restrict__ BT,
    const float* __restrict__ bias,
    void* __restrict__ Cout, int N, int K,
    unsigned short* As, unsigned short* Bs)
{
    const int tid  = threadIdx.x;
    const int wave = tid >> 6, lane = tid & 63;
    const int l15  = lane & 15, l4 = lane >> 4;
    const int wr   = wave >> 1, wc = wave & 1;
    const long rowBase = (long)blockIdx.x * 128;
    const long colBase = (long)blockIdx.y * 128;

    f32x4 acc[4][4];
    #pragma unroll
    for (int m = 0; m < 4; m++)
        #pragma unroll
        for (int n = 0; n < 4; n++)
            acc[m][n] = (f32x4){0.f, 0.f, 0.f, 0.f};

    const int c0    = wave * 2;
    const int srow0 = c0 * 16 + (lane >> 2);
    const int srow1 = srow0 + 16;
    const int skk   = (lane & 3) * 8;

    for (int k0 = 0; k0 < K; k0 += 32) {
        GLL16(A  + (rowBase + srow0) * K + k0 + skk, As + c0 * 512);
        GLL16(A  + (rowBase + srow1) * K + k0 + skk, As + (c0 + 1) * 512);
        GLL16(BT + (colBase + srow0) * K + k0 + skk, Bs + c0 * 512);
        GLL16(BT + (colBase + srow1) * K + k0 + skk, Bs + (c0 + 1) * 512);
        __syncthreads();
        bf16x8 af[4], bfr[4];
        #pragma unroll
        for (int m = 0; m < 4; m++)
            af[m] = *(const bf16x8*)(As + (wr*64 + m*16 + l15) * 32 + l4 * 8);
        #pragma unroll
        for (int n = 0; n < 4; n++)
            bfr[n] = *(const bf16x8*)(Bs + (wc*64 + n*16 + l15) * 32 + l4 * 8);
        #pragma unroll
        for (int m = 0; m < 4; m++)
            #pragma unroll
            for (int n = 0; n < 4; n++)
                acc[m][n] = __builtin_amdgcn_mfma_f32_16x16x32_bf16(af[m], bfr[n], acc[m][n], 0, 0, 0);
        __syncthreads();
    }

    #pragma unroll
    for (int m = 0; m < 4; m++) {
        const long row = rowBase + wr*64 + m*16 + l4*4;
        #pragma unroll
        for (int n = 0; n < 4; n++) {
            const long col = colBase + wc*64 + n*16 + l15;
            const float bv = bias[col];
            #pragma unroll
            for (int r = 0; r < 4; r++) {
                const float vv = acc[m][n][r] + bv;
                if (OUTF32) ((float*)Cout)[(row + r) * N + col] = vv;
                else        ((unsigned short*)Cout)[(row + r) * N + col] = f2b(vv);
            }
        }
    }
}

__global__ __launch_bounds__(256) void gemm_bias_f32(
    const unsigned short* __restrict__ A,
    const unsigned short* __restrict__ BT,
    const float* __restrict__ bias,
    float* __restrict__ Cout, int N, int K)
{
    __shared__ unsigned short As[128 * 32];
    __shared__ unsigned short Bs[128 * 32];
    gemm_body<1>(A, BT, bias, (void*)Cout, N, K, As, Bs);
}

__global__ __launch_bounds__(256) void gemm3(
    const unsigned short* __restrict__ Abase,
    const unsigned short* __restrict__ WT,
    const float* __restrict__ bq, const float* __restrict__ bk, const float* __restrict__ bv,
    unsigned short* __restrict__ Cbase)
{
    __shared__ unsigned short As[128 * 32];
    __shared__ unsigned short Bs[128 * 32];
    const int z = blockIdx.z;
    const unsigned short* A  = Abase + (long)z * 4194304;
    const unsigned short* BT = WT    + (long)z * 1048576;
    unsigned short*       C  = Cbase + (long)z * 4194304;
    const float* bias = (z == 0) ? bq : (z == 1) ? bk : bv;
    gemm_body<0>(A, BT, bias, (void*)C, 1024, 1024, As, Bs);
}

// ---------------- fused attention: producer/consumer wave specialization ------
// Waves 0-3 (producers): each owns a 16i x 16j patch, computes QK^T for ALL 16
// heads -> the 16 head-scores of each (i,j) are LANE-LOCAL across the 16 accs
// -> register-local softmax (no S buffer, no exchange). Writes P[h][j][i-pack]
// (b64 per head) into a double-buffered LDS P.
// Waves 4-7 (consumers): 4 heads each; read P (scalar u16), PV-MFMA into
// persistent O-acc, packed-Vf coalesced loads.
// ONE barrier per group; producer MFMA/VALU overlaps consumer MFMA/LDS per SIMD.
__global__ __launch_bounds__(512, 1) void attn_fused(
    const unsigned short* __restrict__ Q,    // [4096][1024]
    const unsigned short* __restrict__ Kf_,  // packed [4][64][32][64][8]
    const unsigned short* __restrict__ Vf_,  // packed [4][32][64][64][8]
    const int* __restrict__ mask,            // [1024*1024]
    unsigned short* __restrict__ P0,
    unsigned short* __restrict__ P1)
{
    // P buffers: 2 x [16 h][32 j][36 i-slots] bf16 (i padded 32->36: stride 18
    // dwords makes the consumer's j-strided scalar reads ~4-way instead of 8-way)
    __shared__ __align__(16) unsigned char Pb[73728];

    const int tid = threadIdx.x, w = tid >> 6, lane = tid & 63;
    const int l15 = lane & 15, l4 = lane >> 4;

    // bijective XCD swizzle: 256 blocks -> 32 consecutive wg per XCD
    const int bid = blockIdx.x;
    const int wg  = (bid & 7) * 32 + (bid >> 3);
    const int b   = wg >> 6;
    const int jh  = (wg >> 5) & 1;
    const int i0  = (wg & 31) << 5;

    const unsigned short* Kfb = Kf_ + (long)b * 1048576;
    const unsigned short* Vfb = Vf_ + (long)b * 1048576;
    unsigned short* Pout = (jh == 0) ? P0 : P1;

    if (w < 4) {
        // ================= producer: QK^T + lane-local head-softmax ==========
        const int iw = w >> 1, jw = w & 1;
        const int irow = i0 + iw * 16;

        bf16x8 qf[16][2];   // all 16 heads, K=64 (128 VGPR, persistent)
        #pragma unroll
        for (int h = 0; h < 16; h++)
            #pragma unroll
            for (int ks = 0; ks < 2; ks++)
                qf[h][ks] = *(const bf16x8*)(Q + (long)(b*1024 + irow + l15) * 1024
                                              + h * 64 + ks * 32 + l4 * 8);

        for (int g = 0; g < 16; ++g) {
            const int jt = jh * 32 + g * 2 + jw;
            int mk[4];
            #pragma unroll
            for (int r = 0; r < 4; r++)
                mk[r] = mask[(irow + l4*4 + r) * 1024 + (jh << 9) + g*32 + jw*16 + l15];

            // QK^T, 16 heads: acc[h][r] = S[h][i=l4*4+r][j=l15]  (lane-local in h!)
            f32x4 acc[16];
            #pragma unroll
            for (int h = 0; h < 16; h++) {
                const bf16x8 k0 = *(const bf16x8*)(Kfb + jt * 16384 + (h*2    ) * 512 + lane * 8);
                const bf16x8 k1 = *(const bf16x8*)(Kfb + jt * 16384 + (h*2 + 1) * 512 + lane * 8);
                f32x4 s = (f32x4){0.f, 0.f, 0.f, 0.f};
                s = __builtin_amdgcn_mfma_f32_16x16x32_bf16(qf[h][0], k0, s, 0, 0, 0);
                s = __builtin_amdgcn_mfma_f32_16x16x32_bf16(qf[h][1], k1, s, 0, 0, 0);
                acc[h] = s;
            }

            // register-local softmax over h, in place on acc
            float inv[4];
            #pragma unroll
            for (int r = 0; r < 4; r++) {
                float Z = 0.f;
                #pragma unroll
                for (int h = 0; h < 16; h++) {
                    float x = acc[h][r] * 0.18033688f;   // 0.125 * log2(e)
                    if (mk[r] == 0) x = -__builtin_inff();
                    float e; asm("v_exp_f32 %0, %1" : "=v"(e) : "v"(x));
                    acc[h][r] = e; Z += e;
                }
                float iv; asm("v_rcp_f32 %0, %1" : "=v"(iv) : "v"(Z));
                inv[r] = iv;
            }

            // P write: per head, 4 r-values are i-contiguous -> one b64
            unsigned char* buf = Pb + (g & 1) * 36864;
            #pragma unroll
            for (int h = 0; h < 16; h++) {
                const unsigned a0 = (__float_as_uint(acc[h][0] * inv[0]) + 0x8000u) >> 16;
                const unsigned a1 = (__float_as_uint(acc[h][1] * inv[1]) + 0x8000u) & 0xffff0000u;
                const unsigned a2 = (__float_as_uint(acc[h][2] * inv[2]) + 0x8000u) >> 16;
                const unsigned a3 = (__float_as_uint(acc[h][3] * inv[3]) + 0x8000u) & 0xffff0000u;
                uint2 pr; pr.x = a0 | a1; pr.y = a2 | a3;
                *(uint2*)(buf + ((h*32 + jw*16 + l15) * 36 + iw*16 + l4*4) * 2) = pr;
            }
            LGKM0; BAR;    // barrier #(g+1): P[g] published
        }
    } else {
        // ================= consumer: PV =====================================
        const int hb = (w - 4) * 4;    // 4 heads per consumer wave

        f32x4 acc[4][2][4];   // [h'][isub][n] (128 VGPR, persistent)
        #pragma unroll
        for (int hq = 0; hq < 4; hq++)
            #pragma unroll
            for (int is = 0; is < 2; is++)
                #pragma unroll
                for (int n = 0; n < 4; n++)
                    acc[hq][is][n] = (f32x4){0.f, 0.f, 0.f, 0.f};

        bf16x8 vf[4][4];
        #pragma unroll
        for (int hq = 0; hq < 4; hq++)
            #pragma unroll
            for (int n = 0; n < 4; n++)
                vf[hq][n] = *(const bf16x8*)(Vfb + (long)(jh*16) * 32768
                                               + ((hb + hq) * 4 + n) * 512 + lane * 8);

        for (int g = 0; g < 16; ++g) {
            LGKM0; BAR;    // barrier #(g+1): P[g] ready; prev pa reads drained
            const unsigned char* buf = Pb + (g & 1) * 36864;
            #pragma unroll
            for (int hq = 0; hq < 4; hq++)
                #pragma unroll
                for (int is = 0; is < 2; is++) {
                    bf16x8 pa;
                    #pragma unroll
                    for (int e = 0; e < 8; e++)
                        pa[e] = *(const short*)(buf +
                            (((hb + hq)*32 + l4*8 + e) * 36 + is*16 + l15) * 2);
                    #pragma unroll
                    for (int n = 0; n < 4; n++)
                        acc[hq][is][n] = __builtin_amdgcn_mfma_f32_16x16x32_bf16(
                            pa, vf[hq][n], acc[hq][is][n], 0, 0, 0);
                }
            if (g < 15) {
                #pragma unroll
                for (int hq = 0; hq < 4; hq++)
                    #pragma unroll
                    for (int n = 0; n < 4; n++)
                        vf[hq][n] = *(const bf16x8*)(Vfb + (long)(jh*16 + g + 1) * 32768
                                                       + ((hb + hq) * 4 + n) * 512 + lane * 8);
            }
        }

        // epilogue: bf16 partial
        #pragma unroll
        for (int hq = 0; hq < 4; hq++)
            #pragma unroll
            for (int is = 0; is < 2; is++)
                #pragma unroll
                for (int n = 0; n < 4; n++)
                    #pragma unroll
                    for (int r = 0; r < 4; r++) {
                        const long row = b*1024 + i0 + is*16 + l4*4 + r;
                        Pout[row * 1024 + (hb + hq) * 64 + n * 16 + l15] = f2b(acc[hq][is][n][r]);
                    }
    }
}

// ---------------- reduce: P0 += P1 (bf16, in place) ---------------------------
__global__ __launch_bounds__(256) void addp(
    unsigned short* __restrict__ P0, const unsigned short* __restrict__ P1)
{
    const long i = ((long)blockIdx.x * 256 + threadIdx.x) * 8;
    ushort4 a0 = *(const ushort4*)(P0 + i);
    ushort4 a1 = *(const ushort4*)(P0 + i + 4);
    ushort4 b0 = *(const ushort4*)(P1 + i);
    ushort4 b1 = *(const ushort4*)(P1 + i + 4);
    ushort4 o0, o1;
    o0.x = f2b(b2f(a0.x) + b2f(b0.x)); o0.y = f2b(b2f(a0.y) + b2f(b0.y));
    o0.z = f2b(b2f(a0.z) + b2f(b0.z)); o0.w = f2b(b2f(a0.w) + b2f(b0.w));
    o1.x = f2b(b2f(a1.x) + b2f(b1.x)); o1.y = f2b(b2f(a1.y) + b2f(b1.y));
    o1.z = f2b(b2f(a1.z) + b2f(b1.z)); o1.w = f2b(b2f(a1.w) + b2f(b1.w));
    *(ushort4*)(P0 + i) = o0;
    *(ushort4*)(P0 + i + 4) = o1;
}

extern "C" void kernel_launch(void* const* d_in, const int* in_sizes, int n_in,
                              void* d_out, int out_size, void* d_ws, size_t ws_size,
                              hipStream_t stream)
{
    const float* q    = (const float*)d_in[0];
    const float* k    = (const float*)d_in[1];
    const float* v    = (const float*)d_in[2];
    const int*   mask = (const int*)  d_in[3];
    const float* Wq   = (const float*)d_in[4];
    const float* bq   = (const float*)d_in[5];
    const float* Wk   = (const float*)d_in[6];
    const float* bk   = (const float*)d_in[7];
    const float* Wv   = (const float*)d_in[8];
    const float* bv   = (const float*)d_in[9];
    const float* Wo   = (const float*)d_in[10];
    const float* bo   = (const float*)d_in[11];

    unsigned short* ws = (unsigned short*)d_ws;
    const long MS = 1048576;
    unsigned short* WT  = ws;             // 4 transposed weights      [0,4M)
    unsigned short* Xq  = ws + 4*MS;      // bf16 query  -> later Kf   [4M,8M)
    unsigned short* Xk  = ws + 8*MS;      // bf16 key    -> later P0   [8M,12M)
    unsigned short* Xv  = ws + 12*MS;     // bf16 value  -> later Vf   [12M,16M)
    unsigned short* Qm  = ws + 16*MS;     // Q projection              [16M,20M)
    unsigned short* Km  = ws + 20*MS;     // K projection              [20M,24M)
    unsigned short* Vm  = ws + 24*MS;     // V projection -> later P1  [24M,28M)
    unsigned short* Kf  = Xq;             // packed K (Xq dead after gemm3)
    unsigned short* Vf  = Xv;             // packed V (Xv dead after gemm3)
    unsigned short* P0  = Xk;             // attn partial jh=0
    unsigned short* P1  = Vm;             // attn partial jh=1 (Vm dead after vf_trans)

    convert_qkv<<<12288, 256, 0, stream>>>(q, k, v, Xq);
    wtrans<<<dim3(32, 32, 4), dim3(32, 8), 0, stream>>>(Wq, Wk, Wv, Wo, WT);
    gemm3<<<dim3(32, 8, 3), 256, 0, stream>>>(Xq, WT, bq, bk, bv, Qm);
    kf_trans<<<dim3(64, 4), 256, 0, stream>>>(Km, Kf);
    vf_trans<<<dim3(32, 4), 256, 0, stream>>>(Vm, Vf);
    attn_fused<<<256, 512, 0, stream>>>(Qm, Kf, Vf, mask, P0, P1);
    addp<<<2048, 256, 0, stream>>>(P0, P1);
    gemm_bias_f32<<<dim3(32, 8), 256, 0, stream>>>(P0, WT + 3*MS, bo, (float*)d_out, 1024, 1024);
}

// Round 16
// 165.655 us; speedup vs baseline: 1.0260x; 1.0260x over previous
//
#include <hip/hip_runtime.h>
#include <hip/hip_bf16.h>

// B=4, S=1024, D=1024, H=16, DH=64. Softmax over HEADS (per (i,j)), per reference.

using f32x4  = __attribute__((ext_vector_type(4))) float;
using f32x2  = __attribute__((ext_vector_type(2))) float;
using bf16x8 = __attribute__((ext_vector_type(8))) short;
using bf16x4 = __attribute__((ext_vector_type(4))) short;

__device__ inline unsigned short f2b(float f){
    unsigned u = __float_as_uint(f);
    unsigned r = (u + 0x7fffu + ((u >> 16) & 1u)) >> 16;
    return (unsigned short)r;
}
__device__ inline float b2f(unsigned short s){
    return __uint_as_float(((unsigned)s) << 16);
}

#define GLL16(gp, lp) __builtin_amdgcn_global_load_lds( \
    (const __attribute__((address_space(1))) void*)(gp), \
    (__attribute__((address_space(3))) void*)(lp), 16, 0, 0)

#define LGKM0 do { asm volatile("s_waitcnt lgkmcnt(0)" ::: "memory"); \
                   __builtin_amdgcn_sched_barrier(0); } while(0)
#define BAR   do { __builtin_amdgcn_s_barrier(); \
                   __builtin_amdgcn_sched_barrier(0); } while(0)

// ---------------- convert q,k,v f32 -> bf16, contiguous [3][4096][1024] -------
__global__ __launch_bounds__(256) void convert_qkv(
    const float* __restrict__ q, const float* __restrict__ k, const float* __restrict__ v,
    unsigned short* __restrict__ dst)
{
    const long gid = (long)blockIdx.x * 256 + threadIdx.x;
    const int  t   = (int)(gid >> 20);
    const long off = (gid & 1048575) << 2;
    const float* src = (t == 0) ? q : (t == 1) ? k : v;
    const float4 x = *(const float4*)(src + off);
    ushort4 o;
    o.x = f2b(x.x); o.y = f2b(x.y); o.z = f2b(x.z); o.w = f2b(x.w);
    *(ushort4*)(dst + (long)t * 4194304 + off) = o;
}

// ---------------- transpose+convert W f32 [k][n] -> bf16 [n][k] ---------------
__global__ __launch_bounds__(256) void wtrans(
    const float* __restrict__ w0, const float* __restrict__ w1,
    const float* __restrict__ w2, const float* __restrict__ w3,
    unsigned short* __restrict__ out)
{
    const float* W = (blockIdx.z == 0) ? w0 : (blockIdx.z == 1) ? w1 : (blockIdx.z == 2) ? w2 : w3;
    unsigned short* O = out + (long)blockIdx.z * 1048576;
    __shared__ float t[32][33];
    const int n0 = blockIdx.x * 32, k0 = blockIdx.y * 32;
    const int tx = threadIdx.x, ty = threadIdx.y;
    #pragma unroll
    for (int i = 0; i < 4; i++)
        t[ty + 8*i][tx] = W[(long)(k0 + ty + 8*i) * 1024 + n0 + tx];
    __syncthreads();
    #pragma unroll
    for (int i = 0; i < 4; i++)
        O[(long)(n0 + ty + 8*i) * 1024 + k0 + tx] = f2b(t[tx][ty + 8*i]);
}

// ---------------- [4096][1024] -> MFMA fragment layout (K or Q) ---------------
// F[b][t(64)][hk(32=h*2+ks)][lane(64)][e(8)]:
//   F(...) = M[b][t*16 + (l&15)][ (hk>>1)*64 + (hk&1)*32 + (l>>4)*8 + e ]
__global__ __launch_bounds__(256) void kf_trans(
    const unsigned short* __restrict__ Km, unsigned short* __restrict__ Kf)
{
    const int b = blockIdx.y, jt = blockIdx.x;
    __shared__ unsigned short t[16][1032];
    const int tid = threadIdx.x;
    #pragma unroll
    for (int p = 0; p < 8; p++) {
        const int idx = p * 2048 + tid * 8;
        const int r = idx >> 10, c = idx & 1023;
        *(uint4*)&t[r][c] = *(const uint4*)(Km + (long)(b*1024 + jt*16 + r) * 1024 + c);
    }
    __syncthreads();
    #pragma unroll
    for (int p = 0; p < 8; p++) {
        const int o  = p * 2048 + tid * 8;
        const int hk = o >> 9;
        const int l  = (o >> 3) & 63;
        const int cc = (hk >> 1) * 64 + (hk & 1) * 32 + (l >> 4) * 8;
        *(uint4*)(Kf + (long)(b*64 + jt) * 16384 + o) = *(const uint4*)&t[l & 15][cc];
    }
}

// ---------------- V -> MFMA fragment layout -----------------------------------
// Vf[b][jg(32)][hn(64=h*4+n)][lane(64)][e(8)]:
//   Vf(...) = Vm[b][jg*32 + (l>>4)*8 + e][ (hn>>2)*64 + (hn&3)*16 + (l&15) ]
__global__ __launch_bounds__(256) void vf_trans(
    const unsigned short* __restrict__ Vm, unsigned short* __restrict__ Vf)
{
    const int b = blockIdx.y, jg = blockIdx.x;
    __shared__ unsigned short t[32][1032];
    const int tid = threadIdx.x;
    #pragma unroll
    for (int p = 0; p < 16; p++) {
        const int idx = p * 2048 + tid * 8;
        const int r = idx >> 10, c = idx & 1023;
        *(uint4*)&t[r][c] = *(const uint4*)(Vm + (long)(b*1024 + jg*32 + r) * 1024 + c);
    }
    __syncthreads();
    #pragma unroll
    for (int p = 0; p < 16; p++) {
        const int o  = p * 2048 + tid * 8;
        const int hn = o >> 9;
        const int l  = (o >> 3) & 63;
        const int col = (hn >> 2) * 64 + (hn & 3) * 16 + (l & 15);
        const int r0  = (l >> 4) * 8;
        unsigned short vv[8];
        #pragma unroll
        for (int e = 0; e < 8; e++) vv[e] = t[r0 + e][col];
        *(uint4*)(Vf + (long)(b*32 + jg) * 32768 + o) = *(const uint4*)vv;
    }
}

// ---------------- GEMM tile body (m97 structure) ------------------------------
template<int OUTF32>
__device__ __forceinline__ void gemm_body(
    const unsigned short* __restrict__ A,
    const unsigned short* __restrict__ BT,
    const float* __restrict__ bias,
    void* __restrict__ Cout, int N, int K,
    unsigned short* As, unsigned short* Bs)
{
    const int tid  = threadIdx.x;
    const int wave = tid >> 6, lane = tid & 63;
    const int l15  = lane & 15, l4 = lane >> 4;
    const int wr   = wave >> 1, wc = wave & 1;
    const long rowBase = (long)blockIdx.x * 128;
    const long colBase = (long)blockIdx.y * 128;

    f32x4 acc[4][4];
    #pragma unroll
    for (int m = 0; m < 4; m++)
        #pragma unroll
        for (int n = 0; n < 4; n++)
            acc[m][n] = (f32x4){0.f, 0.f, 0.f, 0.f};

    const int c0    = wave * 2;
    const int srow0 = c0 * 16 + (lane >> 2);
    const int srow1 = srow0 + 16;
    const int skk   = (lane & 3) * 8;

    for (int k0 = 0; k0 < K; k0 += 32) {
        GLL16(A  + (rowBase + srow0) * K + k0 + skk, As + c0 * 512);
        GLL16(A  + (rowBase + srow1) * K + k0 + skk, As + (c0 + 1) * 512);
        GLL16(BT + (colBase + srow0) * K + k0 + skk, Bs + c0 * 512);
        GLL16(BT + (colBase + srow1) * K + k0 + skk, Bs + (c0 + 1) * 512);
        __syncthreads();
        bf16x8 af[4], bfr[4];
        #pragma unroll
        for (int m = 0; m < 4; m++)
            af[m] = *(const bf16x8*)(As + (wr*64 + m*16 + l15) * 32 + l4 * 8);
        #pragma unroll
        for (int n = 0; n < 4; n++)
            bfr[n] = *(const bf16x8*)(Bs + (wc*64 + n*16 + l15) * 32 + l4 * 8);
        #pragma unroll
        for (int m = 0; m < 4; m++)
            #pragma unroll
            for (int n = 0; n < 4; n++)
                acc[m][n] = __builtin_amdgcn_mfma_f32_16x16x32_bf16(af[m], bfr[n], acc[m][n], 0, 0, 0);
        __syncthreads();
    }

    #pragma unroll
    for (int m = 0; m < 4; m++) {
        const long row = rowBase + wr*64 + m*16 + l4*4;
        #pragma unroll
        for (int n = 0; n < 4; n++) {
            const long col = colBase + wc*64 + n*16 + l15;
            const float bv = bias[col];
            #pragma unroll
            for (int r = 0; r < 4; r++) {
                const float vv = acc[m][n][r] + bv;
                if (OUTF32) ((float*)Cout)[(row + r) * N + col] = vv;
                else        ((unsigned short*)Cout)[(row + r) * N + col] = f2b(vv);
            }
        }
    }
}

__global__ __launch_bounds__(256) void gemm_bias_f32(
    const unsigned short* __restrict__ A,
    const unsigned short* __restrict__ BT,
    const float* __restrict__ bias,
    float* __restrict__ Cout, int N, int K)
{
    __shared__ unsigned short As[128 * 32];
    __shared__ unsigned short Bs[128 * 32];
    gemm_body<1>(A, BT, bias, (void*)Cout, N, K, As, Bs);
}

__global__ __launch_bounds__(256) void gemm3(
    const unsigned short* __restrict__ Abase,
    const unsigned short* __restrict__ WT,
    const float* __restrict__ bq, const float* __restrict__ bk, const float* __restrict__ bv,
    unsigned short* __restrict__ Cbase)
{
    __shared__ unsigned short As[128 * 32];
    __shared__ unsigned short Bs[128 * 32];
    const int z = blockIdx.z;
    const unsigned short* A  = Abase + (long)z * 4194304;
    const unsigned short* BT = WT    + (long)z * 1048576;
    unsigned short*       C  = Cbase + (long)z * 4194304;
    const float* bias = (z == 0) ? bq : (z == 1) ? bk : bv;
    gemm_body<0>(A, BT, bias, (void*)C, 1024, 1024, As, Bs);
}

// ---------------- fused attention: producer/consumer, swapped QK --------------
// Producers (w0-3, patch 16i x 16j): SWAPPED QK mfma(kf, qf) -> lane holds
// S^T: (j = l4*4+r, i = l15) per head-acc -> register softmax over h; P write
// [h][i32][j40] = j-contiguous b64. Consumers (w4-7, 4 heads): pa = ONE b128
// per (h,is) (j-contiguous in layout), PV into persistent O-acc.
// P dbuf 2x40KB = 80KB LDS -> forces 1 block/CU -> full 256-VGPR budget
// (round 15: 2-block heuristic capped 128 VGPR -> producer spilled to scratch).
__global__ __launch_bounds__(512, 1) void attn_fused(
    const unsigned short* __restrict__ Qf_,  // packed [4][64][32][64][8]
    const unsigned short* __restrict__ Kf_,  // packed [4][64][32][64][8]
    const unsigned short* __restrict__ Vf_,  // packed [4][32][64][64][8]
    const int* __restrict__ mask,            // [1024*1024]
    unsigned short* __restrict__ P0,
    unsigned short* __restrict__ P1)
{
    // P: 2 x [16 h][32 i][40 j-slots] bf16 (j padded 32->40: 80B rows keep the
    // consumer's b128 16B-aligned and spread i across banks)
    __shared__ __align__(16) unsigned char Pb[81920];

    const int tid = threadIdx.x, w = tid >> 6, lane = tid & 63;
    const int l15 = lane & 15, l4 = lane >> 4;

    // bijective XCD swizzle: 256 blocks -> 32 consecutive wg per XCD
    const int bid = blockIdx.x;
    const int wg  = (bid & 7) * 32 + (bid >> 3);
    const int b   = wg >> 6;
    const int jh  = (wg >> 5) & 1;
    const int i0  = (wg & 31) << 5;

    const unsigned short* Kfb = Kf_ + (long)b * 1048576;
    const unsigned short* Vfb = Vf_ + (long)b * 1048576;
    unsigned short* Pout = (jh == 0) ? P0 : P1;

    if (w < 4) {
        // ================= producer =========================================
        const int iw = w >> 1, jw = w & 1;
        const int it = ((wg & 31) << 1) + iw;          // 16-row i-tile index

        // qf from packed Qf: coalesced, persistent (128 VGPR)
        bf16x8 qf[16][2];
        #pragma unroll
        for (int h = 0; h < 16; h++)
            #pragma unroll
            for (int ks = 0; ks < 2; ks++)
                qf[h][ks] = *(const bf16x8*)(Qf_ + (long)(b*64 + it) * 16384
                                              + (h*2 + ks) * 512 + lane * 8);

        for (int g = 0; g < 16; ++g) {
            const int jt = jh * 32 + g * 2 + jw;
            // mask at (i = l15, j = l4*4+r)
            int mk[4];
            #pragma unroll
            for (int r = 0; r < 4; r++)
                mk[r] = mask[(i0 + iw*16 + l15) * 1024 + (jh << 9) + g*32 + jw*16 + l4*4 + r];

            // swapped QK: acc[h] = S^T[j = l4*4+r][i = l15]
            f32x4 acc[16];
            #pragma unroll
            for (int h = 0; h < 16; h++) {
                const bf16x8 k0 = *(const bf16x8*)(Kfb + jt * 16384 + (h*2    ) * 512 + lane * 8);
                const bf16x8 k1 = *(const bf16x8*)(Kfb + jt * 16384 + (h*2 + 1) * 512 + lane * 8);
                f32x4 s = (f32x4){0.f, 0.f, 0.f, 0.f};
                s = __builtin_amdgcn_mfma_f32_16x16x32_bf16(k0, qf[h][0], s, 0, 0, 0);
                s = __builtin_amdgcn_mfma_f32_16x16x32_bf16(k1, qf[h][1], s, 0, 0, 0);
                acc[h] = s;
            }

            // register-local softmax over h (per r = per j)
            float inv[4];
            #pragma unroll
            for (int r = 0; r < 4; r++) {
                float Z = 0.f;
                #pragma unroll
                for (int h = 0; h < 16; h++) {
                    float x = acc[h][r] * 0.18033688f;   // 0.125 * log2(e)
                    if (mk[r] == 0) x = -__builtin_inff();
                    float e; asm("v_exp_f32 %0, %1" : "=v"(e) : "v"(x));
                    acc[h][r] = e; Z += e;
                }
                float iv; asm("v_rcp_f32 %0, %1" : "=v"(iv) : "v"(Z));
                inv[r] = iv;
            }

            // P write: per head, r-values are j-contiguous -> one b64
            unsigned char* buf = Pb + (g & 1) * 40960;
            #pragma unroll
            for (int h = 0; h < 16; h++) {
                const unsigned a0 = (__float_as_uint(acc[h][0] * inv[0]) + 0x8000u) >> 16;
                const unsigned a1 = (__float_as_uint(acc[h][1] * inv[1]) + 0x8000u) & 0xffff0000u;
                const unsigned a2 = (__float_as_uint(acc[h][2] * inv[2]) + 0x8000u) >> 16;
                const unsigned a3 = (__float_as_uint(acc[h][3] * inv[3]) + 0x8000u) & 0xffff0000u;
                uint2 pr; pr.x = a0 | a1; pr.y = a2 | a3;
                *(uint2*)(buf + ((h*32 + iw*16 + l15) * 40 + jw*16 + l4*4) * 2) = pr;
            }
            LGKM0; BAR;    // barrier #(g+1): P[g] published
        }
    } else {
        // ================= consumer: PV =====================================
        const int hb = (w - 4) * 4;    // 4 heads per consumer wave

        f32x4 acc[4][2][4];   // [h'][isub][n] (128 VGPR, persistent)
        #pragma unroll
        for (int hq = 0; hq < 4; hq++)
            #pragma unroll
            for (int is = 0; is < 2; is++)
                #pragma unroll
                for (int n = 0; n < 4; n++)
                    acc[hq][is][n] = (f32x4){0.f, 0.f, 0.f, 0.f};

        bf16x8 vf[4][4];
        #pragma unroll
        for (int hq = 0; hq < 4; hq++)
            #pragma unroll
            for (int n = 0; n < 4; n++)
                vf[hq][n] = *(const bf16x8*)(Vfb + (long)(jh*16) * 32768
                                               + ((hb + hq) * 4 + n) * 512 + lane * 8);

        for (int g = 0; g < 16; ++g) {
            LGKM0; BAR;    // barrier #(g+1): P[g] ready; prev pa reads drained
            const unsigned char* buf = Pb + (g & 1) * 40960;
            #pragma unroll
            for (int hq = 0; hq < 4; hq++)
                #pragma unroll
                for (int is = 0; is < 2; is++) {
                    const bf16x8 pa = *(const bf16x8*)(buf +
                        (((hb + hq)*32 + is*16 + l15) * 40 + l4*8) * 2);
                    #pragma unroll
                    for (int n = 0; n < 4; n++)
                        acc[hq][is][n] = __builtin_amdgcn_mfma_f32_16x16x32_bf16(
                            pa, vf[hq][n], acc[hq][is][n], 0, 0, 0);
                }
            if (g < 15) {
                #pragma unroll
                for (int hq = 0; hq < 4; hq++)
                    #pragma unroll
                    for (int n = 0; n < 4; n++)
                        vf[hq][n] = *(const bf16x8*)(Vfb + (long)(jh*16 + g + 1) * 32768
                                                       + ((hb + hq) * 4 + n) * 512 + lane * 8);
            }
        }

        // epilogue: bf16 partial
        #pragma unroll
        for (int hq = 0; hq < 4; hq++)
            #pragma unroll
            for (int is = 0; is < 2; is++)
                #pragma unroll
                for (int n = 0; n < 4; n++)
                    #pragma unroll
                    for (int r = 0; r < 4; r++) {
                        const long row = b*1024 + i0 + is*16 + l4*4 + r;
                        Pout[row * 1024 + (hb + hq) * 64 + n * 16 + l15] = f2b(acc[hq][is][n][r]);
                    }
    }
}

// ---------------- reduce: P0 += P1 (bf16, in place) ---------------------------
__global__ __launch_bounds__(256) void addp(
    unsigned short* __restrict__ P0, const unsigned short* __restrict__ P1)
{
    const long i = ((long)blockIdx.x * 256 + threadIdx.x) * 8;
    ushort4 a0 = *(const ushort4*)(P0 + i);
    ushort4 a1 = *(const ushort4*)(P0 + i + 4);
    ushort4 b0 = *(const ushort4*)(P1 + i);
    ushort4 b1 = *(const ushort4*)(P1 + i + 4);
    ushort4 o0, o1;
    o0.x = f2b(b2f(a0.x) + b2f(b0.x)); o0.y = f2b(b2f(a0.y) + b2f(b0.y));
    o0.z = f2b(b2f(a0.z) + b2f(b0.z)); o0.w = f2b(b2f(a0.w) + b2f(b0.w));
    o1.x = f2b(b2f(a1.x) + b2f(b1.x)); o1.y = f2b(b2f(a1.y) + b2f(b1.y));
    o1.z = f2b(b2f(a1.z) + b2f(b1.z)); o1.w = f2b(b2f(a1.w) + b2f(b1.w));
    *(ushort4*)(P0 + i) = o0;
    *(ushort4*)(P0 + i + 4) = o1;
}

extern "C" void kernel_launch(void* const* d_in, const int* in_sizes, int n_in,
                              void* d_out, int out_size, void* d_ws, size_t ws_size,
                              hipStream_t stream)
{
    const float* q    = (const float*)d_in[0];
    const float* k    = (const float*)d_in[1];
    const float* v    = (const float*)d_in[2];
    const int*   mask = (const int*)  d_in[3];
    const float* Wq   = (const float*)d_in[4];
    const float* bq   = (const float*)d_in[5];
    const float* Wk   = (const float*)d_in[6];
    const float* bk   = (const float*)d_in[7];
    const float* Wv   = (const float*)d_in[8];
    const float* bv   = (const float*)d_in[9];
    const float* Wo   = (const float*)d_in[10];
    const float* bo   = (const float*)d_in[11];

    unsigned short* ws = (unsigned short*)d_ws;
    const long MS = 1048576;
    unsigned short* WT  = ws;             // 4 transposed weights      [0,4M)
    unsigned short* Xq  = ws + 4*MS;      // bf16 query  -> later Kf   [4M,8M)
    unsigned short* Xk  = ws + 8*MS;      // bf16 key    -> later P0   [8M,12M)
    unsigned short* Xv  = ws + 12*MS;     // bf16 value  -> later Vf   [12M,16M)
    unsigned short* Qm  = ws + 16*MS;     // Q projection              [16M,20M)
    unsigned short* Km  = ws + 20*MS;     // K projection -> later Qf  [20M,24M)
    unsigned short* Vm  = ws + 24*MS;     // V projection -> later P1  [24M,28M)
    unsigned short* Kf  = Xq;             // packed K (Xq dead after gemm3)
    unsigned short* Vf  = Xv;             // packed V (Xv dead after gemm3)
    unsigned short* Qf  = Km;             // packed Q (Km dead after kf_trans #1)
    unsigned short* P0  = Xk;             // attn partial jh=0
    unsigned short* P1  = Vm;             // attn partial jh=1 (Vm dead after vf_trans)

    convert_qkv<<<12288, 256, 0, stream>>>(q, k, v, Xq);
    wtrans<<<dim3(32, 32, 4), dim3(32, 8), 0, stream>>>(Wq, Wk, Wv, Wo, WT);
    gemm3<<<dim3(32, 8, 3), 256, 0, stream>>>(Xq, WT, bq, bk, bv, Qm);
    kf_trans<<<dim3(64, 4), 256, 0, stream>>>(Km, Kf);   // K -> packed
    kf_trans<<<dim3(64, 4), 256, 0, stream>>>(Qm, Qf);   // Q -> packed (into Km)
    vf_trans<<<dim3(32, 4), 256, 0, stream>>>(Vm, Vf);
    attn_fused<<<256, 512, 0, stream>>>(Qf, Kf, Vf, mask, P0, P1);
    addp<<<2048, 256, 0, stream>>>(P0, P1);
    gemm_bias_f32<<<dim3(32, 8), 256, 0, stream>>>(P0, WT + 3*MS, bo, (float*)d_out, 1024, 1024);
}

// Round 17
// 150.963 us; speedup vs baseline: 1.1258x; 1.0973x over previous
//
#include <hip/hip_runtime.h>
#include <hip/hip_bf16.h>

// B=4, S=1024, D=1024, H=16, DH=64. Softmax over HEADS (per (i,j)), per reference.

using f32x4  = __attribute__((ext_vector_type(4))) float;
using f32x2  = __attribute__((ext_vector_type(2))) float;
using bf16x8 = __attribute__((ext_vector_type(8))) short;
using bf16x4 = __attribute__((ext_vector_type(4))) short;

__device__ inline unsigned short f2b(float f){
    unsigned u = __float_as_uint(f);
    unsigned r = (u + 0x7fffu + ((u >> 16) & 1u)) >> 16;
    return (unsigned short)r;
}
__device__ inline float b2f(unsigned short s){
    return __uint_as_float(((unsigned)s) << 16);
}

#define GLL16(gp, lp) __builtin_amdgcn_global_load_lds( \
    (const __attribute__((address_space(1))) void*)(gp), \
    (__attribute__((address_space(3))) void*)(lp), 16, 0, 0)

#define LGKM0 do { asm volatile("s_waitcnt lgkmcnt(0)" ::: "memory"); \
                   __builtin_amdgcn_sched_barrier(0); } while(0)
#define BAR   do { __builtin_amdgcn_s_barrier(); \
                   __builtin_amdgcn_sched_barrier(0); } while(0)

// ---------------- convert q,k,v f32 -> bf16, contiguous [3][4096][1024] -------
__global__ __launch_bounds__(256) void convert_qkv(
    const float* __restrict__ q, const float* __restrict__ k, const float* __restrict__ v,
    unsigned short* __restrict__ dst)
{
    const long gid = (long)blockIdx.x * 256 + threadIdx.x;
    const int  t   = (int)(gid >> 20);
    const long off = (gid & 1048575) << 2;
    const float* src = (t == 0) ? q : (t == 1) ? k : v;
    const float4 x = *(const float4*)(src + off);
    ushort4 o;
    o.x = f2b(x.x); o.y = f2b(x.y); o.z = f2b(x.z); o.w = f2b(x.w);
    *(ushort4*)(dst + (long)t * 4194304 + off) = o;
}

// ---------------- transpose+convert W f32 [k][n] -> bf16 [n][k] ---------------
__global__ __launch_bounds__(256) void wtrans(
    const float* __restrict__ w0, const float* __restrict__ w1,
    const float* __restrict__ w2, const float* __restrict__ w3,
    unsigned short* __restrict__ out)
{
    const float* W = (blockIdx.z == 0) ? w0 : (blockIdx.z == 1) ? w1 : (blockIdx.z == 2) ? w2 : w3;
    unsigned short* O = out + (long)blockIdx.z * 1048576;
    __shared__ float t[32][33];
    const int n0 = blockIdx.x * 32, k0 = blockIdx.y * 32;
    const int tx = threadIdx.x, ty = threadIdx.y;
    #pragma unroll
    for (int i = 0; i < 4; i++)
        t[ty + 8*i][tx] = W[(long)(k0 + ty + 8*i) * 1024 + n0 + tx];
    __syncthreads();
    #pragma unroll
    for (int i = 0; i < 4; i++)
        O[(long)(n0 + ty + 8*i) * 1024 + k0 + tx] = f2b(t[tx][ty + 8*i]);
}

// ---------------- GEMM tile body (m97 structure) ------------------------------
template<int OUTF32>
__device__ __forceinline__ void gemm_body(
    const unsigned short* __restrict__ A,
    const unsigned short* __restrict__ BT,
    const float* __restrict__ bias,
    void* __restrict__ Cout, int N, int K,
    unsigned short* As, unsigned short* Bs)
{
    const int tid  = threadIdx.x;
    const int wave = tid >> 6, lane = tid & 63;
    const int l15  = lane & 15, l4 = lane >> 4;
    const int wr   = wave >> 1, wc = wave & 1;
    const long rowBase = (long)blockIdx.x * 128;
    const long colBase = (long)blockIdx.y * 128;

    f32x4 acc[4][4];
    #pragma unroll
    for (int m = 0; m < 4; m++)
        #pragma unroll
        for (int n = 0; n < 4; n++)
            acc[m][n] = (f32x4){0.f, 0.f, 0.f, 0.f};

    const int c0    = wave * 2;
    const int srow0 = c0 * 16 + (lane >> 2);
    const int srow1 = srow0 + 16;
    const int skk   = (lane & 3) * 8;

    for (int k0 = 0; k0 < K; k0 += 32) {
        GLL16(A  + (rowBase + srow0) * K + k0 + skk, As + c0 * 512);
        GLL16(A  + (rowBase + srow1) * K + k0 + skk, As + (c0 + 1) * 512);
        GLL16(BT + (colBase + srow0) * K + k0 + skk, Bs + c0 * 512);
        GLL16(BT + (colBase + srow1) * K + k0 + skk, Bs + (c0 + 1) * 512);
        __syncthreads();
        bf16x8 af[4], bfr[4];
        #pragma unroll
        for (int m = 0; m < 4; m++)
            af[m] = *(const bf16x8*)(As + (wr*64 + m*16 + l15) * 32 + l4 * 8);
        #pragma unroll
        for (int n = 0; n < 4; n++)
            bfr[n] = *(const bf16x8*)(Bs + (wc*64 + n*16 + l15) * 32 + l4 * 8);
        #pragma unroll
        for (int m = 0; m < 4; m++)
            #pragma unroll
            for (int n = 0; n < 4; n++)
                acc[m][n] = __builtin_amdgcn_mfma_f32_16x16x32_bf16(af[m], bfr[n], acc[m][n], 0, 0, 0);
        __syncthreads();
    }

    #pragma unroll
    for (int m = 0; m < 4; m++) {
        const long row = rowBase + wr*64 + m*16 + l4*4;
        #pragma unroll
        for (int n = 0; n < 4; n++) {
            const long col = colBase + wc*64 + n*16 + l15;
            const float bv = bias[col];
            #pragma unroll
            for (int r = 0; r < 4; r++) {
                const float vv = acc[m][n][r] + bv;
                if (OUTF32) ((float*)Cout)[(row + r) * N + col] = vv;
                else        ((unsigned short*)Cout)[(row + r) * N + col] = f2b(vv);
            }
        }
    }
}

__global__ __launch_bounds__(256) void gemm_bias_f32(
    const unsigned short* __restrict__ A,
    const unsigned short* __restrict__ BT,
    const float* __restrict__ bias,
    float* __restrict__ Cout, int N, int K)
{
    __shared__ unsigned short As[128 * 32];
    __shared__ unsigned short Bs[128 * 32];
    gemm_body<1>(A, BT, bias, (void*)Cout, N, K, As, Bs);
}

// ---------------- batched QKV projection GEMMs, PACKED-fragment epilogue ------
// z=0 (Q), z=1 (K): write MFMA K/Q-fragment layout
//   addr = (R>>4)*16384 + (c>>5)*512 + (((c>>3)&3)*16 + (R&15))*8 + (c&7)
// z=2 (V): write MFMA V-fragment layout
//   addr = (R>>5)*32768 + (c>>4)*512 + (((R>>3)&3)*16 + (c&15))*8 + (R&7)
// (inverses of the former kf_trans / vf_trans maps; same store count as
// row-major scalar epilogue -> packing is free, kills 3 transform kernels)
__global__ __launch_bounds__(256) void gemm3(
    const unsigned short* __restrict__ Abase,   // Xq | Xk | Xv (stride 4M elems)
    const unsigned short* __restrict__ WT,      // 3 weights (stride 1M elems)
    const float* __restrict__ bq, const float* __restrict__ bk, const float* __restrict__ bv,
    unsigned short* __restrict__ Cpk)           // Qf | Kf | Vf (stride 4M elems)
{
    __shared__ unsigned short As[128 * 32];
    __shared__ unsigned short Bs[128 * 32];
    const int z = blockIdx.z;
    const unsigned short* A  = Abase + (long)z * 4194304;
    const unsigned short* BT = WT    + (long)z * 1048576;
    unsigned short*       C  = Cpk   + (long)z * 4194304;
    const float* bias = (z == 0) ? bq : (z == 1) ? bk : bv;

    const int tid  = threadIdx.x;
    const int wave = tid >> 6, lane = tid & 63;
    const int l15  = lane & 15, l4 = lane >> 4;
    const int wr   = wave >> 1, wc = wave & 1;
    const int rowBase = blockIdx.x * 128;
    const int colBase = blockIdx.y * 128;
    const int K = 1024;

    f32x4 acc[4][4];
    #pragma unroll
    for (int m = 0; m < 4; m++)
        #pragma unroll
        for (int n = 0; n < 4; n++)
            acc[m][n] = (f32x4){0.f, 0.f, 0.f, 0.f};

    const int c0    = wave * 2;
    const int srow0 = c0 * 16 + (lane >> 2);
    const int srow1 = srow0 + 16;
    const int skk   = (lane & 3) * 8;

    for (int k0 = 0; k0 < K; k0 += 32) {
        GLL16(A  + (long)(rowBase + srow0) * K + k0 + skk, As + c0 * 512);
        GLL16(A  + (long)(rowBase + srow1) * K + k0 + skk, As + (c0 + 1) * 512);
        GLL16(BT + (long)(colBase + srow0) * K + k0 + skk, Bs + c0 * 512);
        GLL16(BT + (long)(colBase + srow1) * K + k0 + skk, Bs + (c0 + 1) * 512);
        __syncthreads();
        bf16x8 af[4], bfr[4];
        #pragma unroll
        for (int m = 0; m < 4; m++)
            af[m] = *(const bf16x8*)(As + (wr*64 + m*16 + l15) * 32 + l4 * 8);
        #pragma unroll
        for (int n = 0; n < 4; n++)
            bfr[n] = *(const bf16x8*)(Bs + (wc*64 + n*16 + l15) * 32 + l4 * 8);
        #pragma unroll
        for (int m = 0; m < 4; m++)
            #pragma unroll
            for (int n = 0; n < 4; n++)
                acc[m][n] = __builtin_amdgcn_mfma_f32_16x16x32_bf16(af[m], bfr[n], acc[m][n], 0, 0, 0);
        __syncthreads();
    }

    #pragma unroll
    for (int m = 0; m < 4; m++) {
        const int R0 = rowBase + wr*64 + m*16 + l4*4;
        #pragma unroll
        for (int n = 0; n < 4; n++) {
            const int c = colBase + wc*64 + n*16 + l15;
            const float bv2 = bias[c];
            #pragma unroll
            for (int r = 0; r < 4; r++) {
                const int R = R0 + r;
                const float vv = acc[m][n][r] + bv2;
                long addr;
                if (z == 2)
                    addr = (long)(R >> 5) * 32768 + (c >> 4) * 512
                         + (((R >> 3) & 3) * 16 + (c & 15)) * 8 + (R & 7);
                else
                    addr = (long)(R >> 4) * 16384 + (c >> 5) * 512
                         + (((c >> 3) & 3) * 16 + (R & 15)) * 8 + (c & 7);
                C[addr] = f2b(vv);
            }
        }
    }
}

// ---------------- fused attention (round-13 structure, verified best) ---------
// Packed Qf/Kf/Vf loads (all coalesced lane*16B), 4 raw-barrier phases,
// S/P alias, 72KB LDS, 128-VGPR cap. + T5 setprio around MFMA clusters.
__global__ __launch_bounds__(512, 2) void attn_fused(
    const unsigned short* __restrict__ Qf_,  // packed [4][64][32][64][8]
    const unsigned short* __restrict__ Kf_,  // packed [4][64][32][64][8]
    const unsigned short* __restrict__ Vf_,  // packed [4][32][64][64][8]
    const int* __restrict__ mask,            // [1024*1024]
    unsigned short* __restrict__ P0,
    unsigned short* __restrict__ P1)
{
    __shared__ __align__(16) unsigned char smem[73728];
    float*         Se = (float*)smem;                 // [512 ij][18 f32] (72B rows)
    float*         So = (float*)(smem + 36864);       // [512 ij][18 f32]
    unsigned char* Pb = smem;                         // [16 h][32 i][72B], aliases Se

    const int tid = threadIdx.x, w = tid >> 6, lane = tid & 63;
    const int l15 = lane & 15, l4 = lane >> 4;
    const int h0  = 2 * w;
    const int sxor = h0 ^ (l4 << 2);

    // bijective XCD swizzle: 256 blocks -> 32 consecutive wg per XCD
    const int bid = blockIdx.x;
    const int wg  = (bid & 7) * 32 + (bid >> 3);
    const int b   = wg >> 6;
    const int jh  = (wg >> 5) & 1;
    const int i0  = (wg & 31) << 5;

    const unsigned short* Kfb = Kf_ + (long)b * 1048576;
    const unsigned short* Vfb = Vf_ + (long)b * 1048576;
    unsigned short* Pout = (jh == 0) ? P0 : P1;

    const int si = tid >> 4, sj = tid & 15;    // softmax thread -> (i row, j col)
    const int xorv = si & 12;                  // un-permutes the S h-slots
    const int mrow = (i0 + si) * 1024 + (jh << 9);

    // ---- Q fragments from packed Qf (coalesced, persistent)
    bf16x8 qf[2][2][2];   // [isub][hh][ks]
    #pragma unroll
    for (int is = 0; is < 2; is++)
        #pragma unroll
        for (int hh = 0; hh < 2; hh++)
            #pragma unroll
            for (int ks = 0; ks < 2; ks++)
                qf[is][hh][ks] = *(const bf16x8*)(Qf_ + (long)(b*64 + (i0 >> 4) + is) * 16384
                                                  + ((h0 + hh) * 2 + ks) * 512 + lane * 8);

#define LOAD_KF(JT) do { \
    _Pragma("unroll") \
    for (int t_ = 0; t_ < 2; t_++) \
        _Pragma("unroll") \
        for (int hh = 0; hh < 2; hh++) \
            _Pragma("unroll") \
            for (int ks = 0; ks < 2; ks++) \
                kf[t_][hh][ks] = *(const bf16x8*)(Kfb + ((JT) + t_) * 16384 \
                                                   + ((h0 + hh) * 2 + ks) * 512 + lane * 8); \
    } while(0)

#define LOAD_VF(JG) do { \
    _Pragma("unroll") \
    for (int hh = 0; hh < 2; hh++) \
        _Pragma("unroll") \
        for (int n = 0; n < 4; n++) \
            vf[hh][n] = *(const bf16x8*)(Vfb + (long)(JG) * 32768 \
                                           + ((h0 + hh) * 4 + n) * 512 + lane * 8); \
    } while(0)

    bf16x8 kf[2][2][2];   // [tile e/o][hh][ks]
    bf16x8 vf[2][4];      // [hh][n]
    LOAD_KF(jh*32);
    LOAD_VF(jh*16);

    f32x4 acc[2][2][4];   // [isub][hh][n]
    #pragma unroll
    for (int is = 0; is < 2; is++)
        #pragma unroll
        for (int hh = 0; hh < 2; hh++)
            #pragma unroll
            for (int n = 0; n < 4; n++)
                acc[is][hh][n] = (f32x4){0.f, 0.f, 0.f, 0.f};

    for (int g = 0; g < 16; ++g) {
        const int mke = mask[mrow + g * 32 + sj];
        const int mko = mask[mrow + g * 32 + 16 + sj];

        // ---- QK^T for both tiles (kf in regs)
        __builtin_amdgcn_s_setprio(1);
        #pragma unroll
        for (int t_ = 0; t_ < 2; t_++) {
            float* St = t_ ? So : Se;
            #pragma unroll
            for (int is = 0; is < 2; is++) {
                f32x4 sv0 = (f32x4){0.f,0.f,0.f,0.f}, sv1 = (f32x4){0.f,0.f,0.f,0.f};
                sv0 = __builtin_amdgcn_mfma_f32_16x16x32_bf16(qf[is][0][0], kf[t_][0][0], sv0, 0, 0, 0);
                sv0 = __builtin_amdgcn_mfma_f32_16x16x32_bf16(qf[is][0][1], kf[t_][0][1], sv0, 0, 0, 0);
                sv1 = __builtin_amdgcn_mfma_f32_16x16x32_bf16(qf[is][1][0], kf[t_][1][0], sv1, 0, 0, 0);
                sv1 = __builtin_amdgcn_mfma_f32_16x16x32_bf16(qf[is][1][1], kf[t_][1][1], sv1, 0, 0, 0);
                #pragma unroll
                for (int r = 0; r < 4; r++) {
                    const int ij = (is*16 + l4*4 + r) * 16 + l15;
                    f32x2 pr; pr[0] = sv0[r]; pr[1] = sv1[r];
                    *(f32x2*)(St + ij * 18 + sxor) = pr;
                }
            }
        }
        __builtin_amdgcn_s_setprio(0);
        LGKM0; BAR;                      // B1: S_e, S_o visible

        if (g < 15) LOAD_KF(jh*32 + (g + 1) * 2);   // coalesced refill for g+1

        // ---- softmax tile e (reads Se); packed result held across B2
        unsigned pe[8];
        {
            const float* sp = Se + tid * 18;
            float tv[16];
            #pragma unroll
            for (int q_ = 0; q_ < 8; q_++) {
                const f32x2 t2 = *(const f32x2*)(sp + q_ * 2);
                tv[q_*2] = t2[0]; tv[q_*2+1] = t2[1];
            }
            float Z = 0.f;
            #pragma unroll
            for (int h = 0; h < 16; h++) {
                float x = tv[h] * 0.18033688f;   // 0.125 * log2(e)
                if (mke == 0) x = -__builtin_inff();
                float e; asm("v_exp_f32 %0, %1" : "=v"(e) : "v"(x));
                tv[h] = e; Z += e;
            }
            float inv; asm("v_rcp_f32 %0, %1" : "=v"(inv) : "v"(Z));
            #pragma unroll
            for (int h = 0; h < 8; h++) {
                const unsigned lo = (__float_as_uint(tv[2*h]   * inv) + 0x8000u) >> 16;
                const unsigned hi = (__float_as_uint(tv[2*h+1] * inv) + 0x8000u) >> 16;
                pe[h] = lo | (hi << 16);
            }
        }
        BAR;                             // B2: ALL Se reads done -> P may overwrite
        #pragma unroll
        for (int h = 0; h < 16; h++) {
            const unsigned short pv = (unsigned short)((h & 1) ? (pe[h >> 1] >> 16) : pe[h >> 1]);
            *(unsigned short*)(Pb + (h ^ xorv) * 2304 + si * 72 + sj * 2) = pv;
        }

        // ---- softmax tile o (reads So: NOT aliased, safe during P writes)
        {
            const float* sp = So + tid * 18;
            float tv[16];
            #pragma unroll
            for (int q_ = 0; q_ < 8; q_++) {
                const f32x2 t2 = *(const f32x2*)(sp + q_ * 2);
                tv[q_*2] = t2[0]; tv[q_*2+1] = t2[1];
            }
            float Z = 0.f;
            #pragma unroll
            for (int h = 0; h < 16; h++) {
                float x = tv[h] * 0.18033688f;
                if (mko == 0) x = -__builtin_inff();
                float e; asm("v_exp_f32 %0, %1" : "=v"(e) : "v"(x));
                tv[h] = e; Z += e;
            }
            float inv; asm("v_rcp_f32 %0, %1" : "=v"(inv) : "v"(Z));
            #pragma unroll
            for (int h = 0; h < 16; h++) {
                const unsigned p16 = (__float_as_uint(tv[h] * inv) + 0x8000u) >> 16;
                *(unsigned short*)(Pb + (h ^ xorv) * 2304 + si * 72 + 32 + sj * 2) = (unsigned short)p16;
            }
        }
        LGKM0; BAR;                      // B3: P visible

        // ---- PV, full K=32 (P rows 72B -> paired b64 reads)
        {
            bf16x8 pa[2][2];
            #pragma unroll
            for (int is = 0; is < 2; is++)
                #pragma unroll
                for (int hh = 0; hh < 2; hh++) {
                    const unsigned char* pr = Pb + (h0 + hh) * 2304 + (is*16 + l15) * 72 + l4 * 16;
                    bf16x4 lo = *(const bf16x4*)(pr);
                    bf16x4 hi = *(const bf16x4*)(pr + 8);
                    pa[is][hh] = (bf16x8){lo[0],lo[1],lo[2],lo[3], hi[0],hi[1],hi[2],hi[3]};
                }
            __builtin_amdgcn_s_setprio(1);
            #pragma unroll
            for (int is = 0; is < 2; is++)
                #pragma unroll
                for (int hh = 0; hh < 2; hh++)
                    #pragma unroll
                    for (int n = 0; n < 4; n++)
                        acc[is][hh][n] = __builtin_amdgcn_mfma_f32_16x16x32_bf16(pa[is][hh], vf[hh][n], acc[is][hh][n], 0, 0, 0);
            __builtin_amdgcn_s_setprio(0);
        }
        if (g < 15) {
            LOAD_VF(jh*16 + g + 1);      // coalesced refill for g+1
            BAR;                         // B4: P reads done; next QK may write Se
        }
    }

    // ---- epilogue: bf16 partial
    #pragma unroll
    for (int is = 0; is < 2; is++)
        #pragma unroll
        for (int hh = 0; hh < 2; hh++)
            #pragma unroll
            for (int n = 0; n < 4; n++)
                #pragma unroll
                for (int r = 0; r < 4; r++) {
                    const long row = b * 1024 + i0 + is * 16 + l4 * 4 + r;
                    Pout[row * 1024 + (h0 + hh) * 64 + n * 16 + l15] = f2b(acc[is][hh][n][r]);
                }
#undef LOAD_KF
#undef LOAD_VF
}

// ---------------- reduce: P0 += P1 (bf16, in place) ---------------------------
__global__ __launch_bounds__(256) void addp(
    unsigned short* __restrict__ P0, const unsigned short* __restrict__ P1)
{
    const long i = ((long)blockIdx.x * 256 + threadIdx.x) * 8;
    ushort4 a0 = *(const ushort4*)(P0 + i);
    ushort4 a1 = *(const ushort4*)(P0 + i + 4);
    ushort4 b0 = *(const ushort4*)(P1 + i);
    ushort4 b1 = *(const ushort4*)(P1 + i + 4);
    ushort4 o0, o1;
    o0.x = f2b(b2f(a0.x) + b2f(b0.x)); o0.y = f2b(b2f(a0.y) + b2f(b0.y));
    o0.z = f2b(b2f(a0.z) + b2f(b0.z)); o0.w = f2b(b2f(a0.w) + b2f(b0.w));
    o1.x = f2b(b2f(a1.x) + b2f(b1.x)); o1.y = f2b(b2f(a1.y) + b2f(b1.y));
    o1.z = f2b(b2f(a1.z) + b2f(b1.z)); o1.w = f2b(b2f(a1.w) + b2f(b1.w));
    *(ushort4*)(P0 + i) = o0;
    *(ushort4*)(P0 + i + 4) = o1;
}

extern "C" void kernel_launch(void* const* d_in, const int* in_sizes, int n_in,
                              void* d_out, int out_size, void* d_ws, size_t ws_size,
                              hipStream_t stream)
{
    const float* q    = (const float*)d_in[0];
    const float* k    = (const float*)d_in[1];
    const float* v    = (const float*)d_in[2];
    const int*   mask = (const int*)  d_in[3];
    const float* Wq   = (const float*)d_in[4];
    const float* bq   = (const float*)d_in[5];
    const float* Wk   = (const float*)d_in[6];
    const float* bk   = (const float*)d_in[7];
    const float* Wv   = (const float*)d_in[8];
    const float* bv   = (const float*)d_in[9];
    const float* Wo   = (const float*)d_in[10];
    const float* bo   = (const float*)d_in[11];

    unsigned short* ws = (unsigned short*)d_ws;
    const long MS = 1048576;
    unsigned short* WT  = ws;             // 4 transposed weights      [0,4M)
    unsigned short* Xq  = ws + 4*MS;      // bf16 query  -> later P1   [4M,8M)
    unsigned short* Xk  = ws + 8*MS;      // bf16 key    -> later P0   [8M,12M)
    unsigned short* Xv  = ws + 12*MS;     // bf16 value                [12M,16M)
    unsigned short* Qf  = ws + 16*MS;     // packed Q projection       [16M,20M)
    unsigned short* Kf  = ws + 20*MS;     // packed K projection       [20M,24M)
    unsigned short* Vf  = ws + 24*MS;     // packed V projection       [24M,28M)
    unsigned short* P0  = Xk;             // attn partial jh=0 (Xk dead after gemm3)
    unsigned short* P1  = Xq;             // attn partial jh=1 (Xq dead after gemm3)

    convert_qkv<<<12288, 256, 0, stream>>>(q, k, v, Xq);
    wtrans<<<dim3(32, 32, 4), dim3(32, 8), 0, stream>>>(Wq, Wk, Wv, Wo, WT);
    gemm3<<<dim3(32, 8, 3), 256, 0, stream>>>(Xq, WT, bq, bk, bv, Qf);
    attn_fused<<<256, 512, 0, stream>>>(Qf, Kf, Vf, mask, P0, P1);
    addp<<<2048, 256, 0, stream>>>(P0, P1);
    gemm_bias_f32<<<dim3(32, 8), 256, 0, stream>>>(P0, WT + 3*MS, bo, (float*)d_out, 1024, 1024);
}

// Round 18
// 144.490 us; speedup vs baseline: 1.1763x; 1.0448x over previous
//
#include <hip/hip_runtime.h>
#include <hip/hip_bf16.h>

// B=4, S=1024, D=1024, H=16, DH=64. Softmax over HEADS (per (i,j)), per reference.

using f32x4  = __attribute__((ext_vector_type(4))) float;
using f32x2  = __attribute__((ext_vector_type(2))) float;
using bf16x8 = __attribute__((ext_vector_type(8))) short;
using bf16x4 = __attribute__((ext_vector_type(4))) short;

__device__ inline unsigned short f2b(float f){
    unsigned u = __float_as_uint(f);
    unsigned r = (u + 0x7fffu + ((u >> 16) & 1u)) >> 16;
    return (unsigned short)r;
}
__device__ inline float b2f(unsigned short s){
    return __uint_as_float(((unsigned)s) << 16);
}

#define GLL16(gp, lp) __builtin_amdgcn_global_load_lds( \
    (const __attribute__((address_space(1))) void*)(gp), \
    (__attribute__((address_space(3))) void*)(lp), 16, 0, 0)

#define LGKM0 do { asm volatile("s_waitcnt lgkmcnt(0)" ::: "memory"); \
                   __builtin_amdgcn_sched_barrier(0); } while(0)
#define BAR   do { __builtin_amdgcn_s_barrier(); \
                   __builtin_amdgcn_sched_barrier(0); } while(0)

// ---------------- convert q,k,v f32 -> bf16, contiguous [3][4096][1024] -------
__global__ __launch_bounds__(256) void convert_qkv(
    const float* __restrict__ q, const float* __restrict__ k, const float* __restrict__ v,
    unsigned short* __restrict__ dst)
{
    const long gid = (long)blockIdx.x * 256 + threadIdx.x;
    const int  t   = (int)(gid >> 20);
    const long off = (gid & 1048575) << 2;
    const float* src = (t == 0) ? q : (t == 1) ? k : v;
    const float4 x = *(const float4*)(src + off);
    ushort4 o;
    o.x = f2b(x.x); o.y = f2b(x.y); o.z = f2b(x.z); o.w = f2b(x.w);
    *(ushort4*)(dst + (long)t * 4194304 + off) = o;
}

// ---------------- transpose+convert W f32 [k][n] -> bf16 [n][k] ---------------
__global__ __launch_bounds__(256) void wtrans(
    const float* __restrict__ w0, const float* __restrict__ w1,
    const float* __restrict__ w2, const float* __restrict__ w3,
    unsigned short* __restrict__ out)
{
    const float* W = (blockIdx.z == 0) ? w0 : (blockIdx.z == 1) ? w1 : (blockIdx.z == 2) ? w2 : w3;
    unsigned short* O = out + (long)blockIdx.z * 1048576;
    __shared__ float t[32][33];
    const int n0 = blockIdx.x * 32, k0 = blockIdx.y * 32;
    const int tx = threadIdx.x, ty = threadIdx.y;
    #pragma unroll
    for (int i = 0; i < 4; i++)
        t[ty + 8*i][tx] = W[(long)(k0 + ty + 8*i) * 1024 + n0 + tx];
    __syncthreads();
    #pragma unroll
    for (int i = 0; i < 4; i++)
        O[(long)(n0 + ty + 8*i) * 1024 + k0 + tx] = f2b(t[tx][ty + 8*i]);
}

// ---------------- GEMM tile body: BK=64, XOR-swizzled LDS ---------------------
// Staging (rule 21, both-sides): lane fetches global chunk (lane&7)^(row&7)
// into LINEAR LDS [128][64]; fragment read applies the same XOR ->
// conflict-free b128 (2 lanes/bank) and half the barrier-drain events of BK=32.
template<int OUTF32>
__device__ __forceinline__ void gemm_body(
    const unsigned short* __restrict__ A,
    const unsigned short* __restrict__ BT,
    const float* __restrict__ bias,
    void* __restrict__ Cout, int N, int K,
    unsigned short* As, unsigned short* Bs)
{
    const int tid  = threadIdx.x;
    const int wave = tid >> 6, lane = tid & 63;
    const int l15  = lane & 15, l4 = lane >> 4;
    const int wr   = wave >> 1, wc = wave & 1;
    const long rowBase = (long)blockIdx.x * 128;
    const long colBase = (long)blockIdx.y * 128;

    f32x4 acc[4][4];
    #pragma unroll
    for (int m = 0; m < 4; m++)
        #pragma unroll
        for (int n = 0; n < 4; n++)
            acc[m][n] = (f32x4){0.f, 0.f, 0.f, 0.f};

    const int srow = wave * 32 + (lane >> 3);                 // +u*8 per GLL16
    const int skk  = (((lane & 7) ^ ((lane >> 3) & 7))) * 8;  // swizzled src chunk
    const int fx   = (l15 & 7);                               // read-back XOR

    for (int k0 = 0; k0 < K; k0 += 64) {
        #pragma unroll
        for (int u = 0; u < 4; u++) {
            GLL16(A  + (rowBase + srow + u*8) * K + k0 + skk, As + (wave*32 + u*8) * 64);
            GLL16(BT + (colBase + srow + u*8) * K + k0 + skk, Bs + (wave*32 + u*8) * 64);
        }
        __syncthreads();
        bf16x8 af[4][2], bfr[4][2];
        #pragma unroll
        for (int m = 0; m < 4; m++)
            #pragma unroll
            for (int kk = 0; kk < 2; kk++) {
                af[m][kk]  = *(const bf16x8*)(As + (wr*64 + m*16 + l15) * 64
                                               + (((kk*4 + l4) ^ fx) * 8));
                bfr[m][kk] = *(const bf16x8*)(Bs + (wc*64 + m*16 + l15) * 64
                                               + (((kk*4 + l4) ^ fx) * 8));
            }
        #pragma unroll
        for (int kk = 0; kk < 2; kk++)
            #pragma unroll
            for (int m = 0; m < 4; m++)
                #pragma unroll
                for (int n = 0; n < 4; n++)
                    acc[m][n] = __builtin_amdgcn_mfma_f32_16x16x32_bf16(af[m][kk], bfr[n][kk], acc[m][n], 0, 0, 0);
        __syncthreads();
    }

    #pragma unroll
    for (int m = 0; m < 4; m++) {
        const long row = rowBase + wr*64 + m*16 + l4*4;
        #pragma unroll
        for (int n = 0; n < 4; n++) {
            const long col = colBase + wc*64 + n*16 + l15;
            const float bv = bias[col];
            #pragma unroll
            for (int r = 0; r < 4; r++) {
                const float vv = acc[m][n][r] + bv;
                if (OUTF32) ((float*)Cout)[(row + r) * N + col] = vv;
                else        ((unsigned short*)Cout)[(row + r) * N + col] = f2b(vv);
            }
        }
    }
}

__global__ __launch_bounds__(256) void gemm_bias_f32(
    const unsigned short* __restrict__ A,
    const unsigned short* __restrict__ BT,
    const float* __restrict__ bias,
    float* __restrict__ Cout, int N, int K)
{
    __shared__ unsigned short As[128 * 64];
    __shared__ unsigned short Bs[128 * 64];
    gemm_body<1>(A, BT, bias, (void*)Cout, N, K, As, Bs);
}

// ---------------- batched QKV projection GEMMs, PACKED-fragment epilogue ------
// z=0 (Q), z=1 (K): addr = (R>>4)*16384 + (c>>5)*512 + (((c>>3)&3)*16+(R&15))*8 + (c&7)
// z=2 (V):          addr = (R>>5)*32768 + (c>>4)*512 + (((R>>3)&3)*16+(c&15))*8 + (R&7)
__global__ __launch_bounds__(256) void gemm3(
    const unsigned short* __restrict__ Abase,   // Xq | Xk | Xv (stride 4M elems)
    const unsigned short* __restrict__ WT,      // 3 weights (stride 1M elems)
    const float* __restrict__ bq, const float* __restrict__ bk, const float* __restrict__ bv,
    unsigned short* __restrict__ Cpk)           // Qf | Kf | Vf (stride 4M elems)
{
    __shared__ unsigned short As[128 * 64];
    __shared__ unsigned short Bs[128 * 64];
    const int z = blockIdx.z;
    const unsigned short* A  = Abase + (long)z * 4194304;
    const unsigned short* BT = WT    + (long)z * 1048576;
    unsigned short*       C  = Cpk   + (long)z * 4194304;
    const float* bias = (z == 0) ? bq : (z == 1) ? bk : bv;

    const int tid  = threadIdx.x;
    const int wave = tid >> 6, lane = tid & 63;
    const int l15  = lane & 15, l4 = lane >> 4;
    const int wr   = wave >> 1, wc = wave & 1;
    const int rowBase = blockIdx.x * 128;
    const int colBase = blockIdx.y * 128;
    const int K = 1024;

    f32x4 acc[4][4];
    #pragma unroll
    for (int m = 0; m < 4; m++)
        #pragma unroll
        for (int n = 0; n < 4; n++)
            acc[m][n] = (f32x4){0.f, 0.f, 0.f, 0.f};

    const int srow = wave * 32 + (lane >> 3);
    const int skk  = (((lane & 7) ^ ((lane >> 3) & 7))) * 8;
    const int fx   = (l15 & 7);

    for (int k0 = 0; k0 < K; k0 += 64) {
        #pragma unroll
        for (int u = 0; u < 4; u++) {
            GLL16(A  + (long)(rowBase + srow + u*8) * K + k0 + skk, As + (wave*32 + u*8) * 64);
            GLL16(BT + (long)(colBase + srow + u*8) * K + k0 + skk, Bs + (wave*32 + u*8) * 64);
        }
        __syncthreads();
        bf16x8 af[4][2], bfr[4][2];
        #pragma unroll
        for (int m = 0; m < 4; m++)
            #pragma unroll
            for (int kk = 0; kk < 2; kk++) {
                af[m][kk]  = *(const bf16x8*)(As + (wr*64 + m*16 + l15) * 64
                                               + (((kk*4 + l4) ^ fx) * 8));
                bfr[m][kk] = *(const bf16x8*)(Bs + (wc*64 + m*16 + l15) * 64
                                               + (((kk*4 + l4) ^ fx) * 8));
            }
        #pragma unroll
        for (int kk = 0; kk < 2; kk++)
            #pragma unroll
            for (int m = 0; m < 4; m++)
                #pragma unroll
                for (int n = 0; n < 4; n++)
                    acc[m][n] = __builtin_amdgcn_mfma_f32_16x16x32_bf16(af[m][kk], bfr[n][kk], acc[m][n], 0, 0, 0);
        __syncthreads();
    }

    #pragma unroll
    for (int m = 0; m < 4; m++) {
        const int R0 = rowBase + wr*64 + m*16 + l4*4;
        #pragma unroll
        for (int n = 0; n < 4; n++) {
            const int c = colBase + wc*64 + n*16 + l15;
            const float bv2 = bias[c];
            #pragma unroll
            for (int r = 0; r < 4; r++) {
                const int R = R0 + r;
                const float vv = acc[m][n][r] + bv2;
                long addr;
                if (z == 2)
                    addr = (long)(R >> 5) * 32768 + (c >> 4) * 512
                         + (((R >> 3) & 3) * 16 + (c & 15)) * 8 + (R & 7);
                else
                    addr = (long)(R >> 4) * 16384 + (c >> 5) * 512
                         + (((c >> 3) & 3) * 16 + (R & 15)) * 8 + (c & 7);
                C[addr] = f2b(vv);
            }
        }
    }
}

// ---------------- fused attention (round-13 structure, verified best) ---------
// Packed Qf/Kf/Vf loads (all coalesced lane*16B), 4 raw-barrier phases,
// S/P alias, 72KB LDS, 128-VGPR cap. + T5 setprio around MFMA clusters.
__global__ __launch_bounds__(512, 2) void attn_fused(
    const unsigned short* __restrict__ Qf_,  // packed [4][64][32][64][8]
    const unsigned short* __restrict__ Kf_,  // packed [4][64][32][64][8]
    const unsigned short* __restrict__ Vf_,  // packed [4][32][64][64][8]
    const int* __restrict__ mask,            // [1024*1024]
    unsigned short* __restrict__ P0,
    unsigned short* __restrict__ P1)
{
    __shared__ __align__(16) unsigned char smem[73728];
    float*         Se = (float*)smem;                 // [512 ij][18 f32] (72B rows)
    float*         So = (float*)(smem + 36864);       // [512 ij][18 f32]
    unsigned char* Pb = smem;                         // [16 h][32 i][72B], aliases Se

    const int tid = threadIdx.x, w = tid >> 6, lane = tid & 63;
    const int l15 = lane & 15, l4 = lane >> 4;
    const int h0  = 2 * w;
    const int sxor = h0 ^ (l4 << 2);

    // bijective XCD swizzle: 256 blocks -> 32 consecutive wg per XCD
    const int bid = blockIdx.x;
    const int wg  = (bid & 7) * 32 + (bid >> 3);
    const int b   = wg >> 6;
    const int jh  = (wg >> 5) & 1;
    const int i0  = (wg & 31) << 5;

    const unsigned short* Kfb = Kf_ + (long)b * 1048576;
    const unsigned short* Vfb = Vf_ + (long)b * 1048576;
    unsigned short* Pout = (jh == 0) ? P0 : P1;

    const int si = tid >> 4, sj = tid & 15;    // softmax thread -> (i row, j col)
    const int xorv = si & 12;                  // un-permutes the S h-slots
    const int mrow = (i0 + si) * 1024 + (jh << 9);

    // ---- Q fragments from packed Qf (coalesced, persistent)
    bf16x8 qf[2][2][2];   // [isub][hh][ks]
    #pragma unroll
    for (int is = 0; is < 2; is++)
        #pragma unroll
        for (int hh = 0; hh < 2; hh++)
            #pragma unroll
            for (int ks = 0; ks < 2; ks++)
                qf[is][hh][ks] = *(const bf16x8*)(Qf_ + (long)(b*64 + (i0 >> 4) + is) * 16384
                                                  + ((h0 + hh) * 2 + ks) * 512 + lane * 8);

#define LOAD_KF(JT) do { \
    _Pragma("unroll") \
    for (int t_ = 0; t_ < 2; t_++) \
        _Pragma("unroll") \
        for (int hh = 0; hh < 2; hh++) \
            _Pragma("unroll") \
            for (int ks = 0; ks < 2; ks++) \
                kf[t_][hh][ks] = *(const bf16x8*)(Kfb + ((JT) + t_) * 16384 \
                                                   + ((h0 + hh) * 2 + ks) * 512 + lane * 8); \
    } while(0)

#define LOAD_VF(JG) do { \
    _Pragma("unroll") \
    for (int hh = 0; hh < 2; hh++) \
        _Pragma("unroll") \
        for (int n = 0; n < 4; n++) \
            vf[hh][n] = *(const bf16x8*)(Vfb + (long)(JG) * 32768 \
                                           + ((h0 + hh) * 4 + n) * 512 + lane * 8); \
    } while(0)

    bf16x8 kf[2][2][2];   // [tile e/o][hh][ks]
    bf16x8 vf[2][4];      // [hh][n]
    LOAD_KF(jh*32);
    LOAD_VF(jh*16);

    f32x4 acc[2][2][4];   // [isub][hh][n]
    #pragma unroll
    for (int is = 0; is < 2; is++)
        #pragma unroll
        for (int hh = 0; hh < 2; hh++)
            #pragma unroll
            for (int n = 0; n < 4; n++)
                acc[is][hh][n] = (f32x4){0.f, 0.f, 0.f, 0.f};

    for (int g = 0; g < 16; ++g) {
        const int mke = mask[mrow + g * 32 + sj];
        const int mko = mask[mrow + g * 32 + 16 + sj];

        // ---- QK^T for both tiles (kf in regs)
        __builtin_amdgcn_s_setprio(1);
        #pragma unroll
        for (int t_ = 0; t_ < 2; t_++) {
            float* St = t_ ? So : Se;
            #pragma unroll
            for (int is = 0; is < 2; is++) {
                f32x4 sv0 = (f32x4){0.f,0.f,0.f,0.f}, sv1 = (f32x4){0.f,0.f,0.f,0.f};
                sv0 = __builtin_amdgcn_mfma_f32_16x16x32_bf16(qf[is][0][0], kf[t_][0][0], sv0, 0, 0, 0);
                sv0 = __builtin_amdgcn_mfma_f32_16x16x32_bf16(qf[is][0][1], kf[t_][0][1], sv0, 0, 0, 0);
                sv1 = __builtin_amdgcn_mfma_f32_16x16x32_bf16(qf[is][1][0], kf[t_][1][0], sv1, 0, 0, 0);
                sv1 = __builtin_amdgcn_mfma_f32_16x16x32_bf16(qf[is][1][1], kf[t_][1][1], sv1, 0, 0, 0);
                #pragma unroll
                for (int r = 0; r < 4; r++) {
                    const int ij = (is*16 + l4*4 + r) * 16 + l15;
                    f32x2 pr; pr[0] = sv0[r]; pr[1] = sv1[r];
                    *(f32x2*)(St + ij * 18 + sxor) = pr;
                }
            }
        }
        __builtin_amdgcn_s_setprio(0);
        LGKM0; BAR;                      // B1: S_e, S_o visible

        if (g < 15) LOAD_KF(jh*32 + (g + 1) * 2);   // coalesced refill for g+1

        // ---- softmax tile e (reads Se); packed result held across B2
        unsigned pe[8];
        {
            const float* sp = Se + tid * 18;
            float tv[16];
            #pragma unroll
            for (int q_ = 0; q_ < 8; q_++) {
                const f32x2 t2 = *(const f32x2*)(sp + q_ * 2);
                tv[q_*2] = t2[0]; tv[q_*2+1] = t2[1];
            }
            float Z = 0.f;
            #pragma unroll
            for (int h = 0; h < 16; h++) {
                float x = tv[h] * 0.18033688f;   // 0.125 * log2(e)
                if (mke == 0) x = -__builtin_inff();
                float e; asm("v_exp_f32 %0, %1" : "=v"(e) : "v"(x));
                tv[h] = e; Z += e;
            }
            float inv; asm("v_rcp_f32 %0, %1" : "=v"(inv) : "v"(Z));
            #pragma unroll
            for (int h = 0; h < 8; h++) {
                const unsigned lo = (__float_as_uint(tv[2*h]   * inv) + 0x8000u) >> 16;
                const unsigned hi = (__float_as_uint(tv[2*h+1] * inv) + 0x8000u) >> 16;
                pe[h] = lo | (hi << 16);
            }
        }
        BAR;                             // B2: ALL Se reads done -> P may overwrite
        #pragma unroll
        for (int h = 0; h < 16; h++) {
            const unsigned short pv = (unsigned short)((h & 1) ? (pe[h >> 1] >> 16) : pe[h >> 1]);
            *(unsigned short*)(Pb + (h ^ xorv) * 2304 + si * 72 + sj * 2) = pv;
        }

        // ---- softmax tile o (reads So: NOT aliased, safe during P writes)
        {
            const float* sp = So + tid * 18;
            float tv[16];
            #pragma unroll
            for (int q_ = 0; q_ < 8; q_++) {
                const f32x2 t2 = *(const f32x2*)(sp + q_ * 2);
                tv[q_*2] = t2[0]; tv[q_*2+1] = t2[1];
            }
            float Z = 0.f;
            #pragma unroll
            for (int h = 0; h < 16; h++) {
                float x = tv[h] * 0.18033688f;
                if (mko == 0) x = -__builtin_inff();
                float e; asm("v_exp_f32 %0, %1" : "=v"(e) : "v"(x));
                tv[h] = e; Z += e;
            }
            float inv; asm("v_rcp_f32 %0, %1" : "=v"(inv) : "v"(Z));
            #pragma unroll
            for (int h = 0; h < 16; h++) {
                const unsigned p16 = (__float_as_uint(tv[h] * inv) + 0x8000u) >> 16;
                *(unsigned short*)(Pb + (h ^ xorv) * 2304 + si * 72 + 32 + sj * 2) = (unsigned short)p16;
            }
        }
        LGKM0; BAR;                      // B3: P visible

        // ---- PV, full K=32 (P rows 72B -> paired b64 reads)
        {
            bf16x8 pa[2][2];
            #pragma unroll
            for (int is = 0; is < 2; is++)
                #pragma unroll
                for (int hh = 0; hh < 2; hh++) {
                    const unsigned char* pr = Pb + (h0 + hh) * 2304 + (is*16 + l15) * 72 + l4 * 16;
                    bf16x4 lo = *(const bf16x4*)(pr);
                    bf16x4 hi = *(const bf16x4*)(pr + 8);
                    pa[is][hh] = (bf16x8){lo[0],lo[1],lo[2],lo[3], hi[0],hi[1],hi[2],hi[3]};
                }
            __builtin_amdgcn_s_setprio(1);
            #pragma unroll
            for (int is = 0; is < 2; is++)
                #pragma unroll
                for (int hh = 0; hh < 2; hh++)
                    #pragma unroll
                    for (int n = 0; n < 4; n++)
                        acc[is][hh][n] = __builtin_amdgcn_mfma_f32_16x16x32_bf16(pa[is][hh], vf[hh][n], acc[is][hh][n], 0, 0, 0);
            __builtin_amdgcn_s_setprio(0);
        }
        if (g < 15) {
            LOAD_VF(jh*16 + g + 1);      // coalesced refill for g+1
            BAR;                         // B4: P reads done; next QK may write Se
        }
    }

    // ---- epilogue: bf16 partial
    #pragma unroll
    for (int is = 0; is < 2; is++)
        #pragma unroll
        for (int hh = 0; hh < 2; hh++)
            #pragma unroll
            for (int n = 0; n < 4; n++)
                #pragma unroll
                for (int r = 0; r < 4; r++) {
                    const long row = b * 1024 + i0 + is * 16 + l4 * 4 + r;
                    Pout[row * 1024 + (h0 + hh) * 64 + n * 16 + l15] = f2b(acc[is][hh][n][r]);
                }
#undef LOAD_KF
#undef LOAD_VF
}

// ---------------- reduce: P0 += P1 (bf16, in place) ---------------------------
__global__ __launch_bounds__(256) void addp(
    unsigned short* __restrict__ P0, const unsigned short* __restrict__ P1)
{
    const long i = ((long)blockIdx.x * 256 + threadIdx.x) * 8;
    ushort4 a0 = *(const ushort4*)(P0 + i);
    ushort4 a1 = *(const ushort4*)(P0 + i + 4);
    ushort4 b0 = *(const ushort4*)(P1 + i);
    ushort4 b1 = *(const ushort4*)(P1 + i + 4);
    ushort4 o0, o1;
    o0.x = f2b(b2f(a0.x) + b2f(b0.x)); o0.y = f2b(b2f(a0.y) + b2f(b0.y));
    o0.z = f2b(b2f(a0.z) + b2f(b0.z)); o0.w = f2b(b2f(a0.w) + b2f(b0.w));
    o1.x = f2b(b2f(a1.x) + b2f(b1.x)); o1.y = f2b(b2f(a1.y) + b2f(b1.y));
    o1.z = f2b(b2f(a1.z) + b2f(b1.z)); o1.w = f2b(b2f(a1.w) + b2f(b1.w));
    *(ushort4*)(P0 + i) = o0;
    *(ushort4*)(P0 + i + 4) = o1;
}

extern "C" void kernel_launch(void* const* d_in, const int* in_sizes, int n_in,
                              void* d_out, int out_size, void* d_ws, size_t ws_size,
                              hipStream_t stream)
{
    const float* q    = (const float*)d_in[0];
    const float* k    = (const float*)d_in[1];
    const float* v    = (const float*)d_in[2];
    const int*   mask = (const int*)  d_in[3];
    const float* Wq   = (const float*)d_in[4];
    const float* bq   = (const float*)d_in[5];
    const float* Wk   = (const float*)d_in[6];
    const float* bk   = (const float*)d_in[7];
    const float* Wv   = (const float*)d_in[8];
    const float* bv   = (const float*)d_in[9];
    const float* Wo   = (const float*)d_in[10];
    const float* bo   = (const float*)d_in[11];

    unsigned short* ws = (unsigned short*)d_ws;
    const long MS = 1048576;
    unsigned short* WT  = ws;             // 4 transposed weights      [0,4M)
    unsigned short* Xq  = ws + 4*MS;      // bf16 query  -> later P1   [4M,8M)
    unsigned short* Xk  = ws + 8*MS;      // bf16 key    -> later P0   [8M,12M)
    unsigned short* Xv  = ws + 12*MS;     // bf16 value                [12M,16M)
    unsigned short* Qf  = ws + 16*MS;     // packed Q projection       [16M,20M)
    unsigned short* Kf  = ws + 20*MS;     // packed K projection       [20M,24M)
    unsigned short* Vf  = ws + 24*MS;     // packed V projection       [24M,28M)
    unsigned short* P0  = Xk;             // attn partial jh=0 (Xk dead after gemm3)
    unsigned short* P1  = Xq;             // attn partial jh=1 (Xq dead after gemm3)

    convert_qkv<<<12288, 256, 0, stream>>>(q, k, v, Xq);
    wtrans<<<dim3(32, 32, 4), dim3(32, 8), 0, stream>>>(Wq, Wk, Wv, Wo, WT);
    gemm3<<<dim3(32, 8, 3), 256, 0, stream>>>(Xq, WT, bq, bk, bv, Qf);
    attn_fused<<<256, 512, 0, stream>>>(Qf, Kf, Vf, mask, P0, P1);
    addp<<<2048, 256, 0, stream>>>(P0, P1);
    gemm_bias_f32<<<dim3(32, 8), 256, 0, stream>>>(P0, WT + 3*MS, bo, (float*)d_out, 1024, 1024);
}

// Round 19
// 143.678 us; speedup vs baseline: 1.1829x; 1.0056x over previous
//
#include <hip/hip_runtime.h>
#include <hip/hip_bf16.h>

// B=4, S=1024, D=1024, H=16, DH=64. Softmax over HEADS (per (i,j)), per reference.

using f32x4  = __attribute__((ext_vector_type(4))) float;
using f32x2  = __attribute__((ext_vector_type(2))) float;
using bf16x8 = __attribute__((ext_vector_type(8))) short;
using bf16x4 = __attribute__((ext_vector_type(4))) short;

__device__ inline unsigned short f2b(float f){
    unsigned u = __float_as_uint(f);
    unsigned r = (u + 0x7fffu + ((u >> 16) & 1u)) >> 16;
    return (unsigned short)r;
}
__device__ inline float b2f(unsigned short s){
    return __uint_as_float(((unsigned)s) << 16);
}

#define GLL16(gp, lp) __builtin_amdgcn_global_load_lds( \
    (const __attribute__((address_space(1))) void*)(gp), \
    (__attribute__((address_space(3))) void*)(lp), 16, 0, 0)

#define LGKM0 do { asm volatile("s_waitcnt lgkmcnt(0)" ::: "memory"); \
                   __builtin_amdgcn_sched_barrier(0); } while(0)
#define BAR   do { __builtin_amdgcn_s_barrier(); \
                   __builtin_amdgcn_sched_barrier(0); } while(0)

// ---------------- prep: convert q,k,v f32->bf16  +  transpose weights ---------
// blocks [0,12288): qkv convert (each 1024 f32). blocks [12288,16384): wtrans.
__global__ __launch_bounds__(256) void prep(
    const float* __restrict__ q, const float* __restrict__ k, const float* __restrict__ v,
    const float* __restrict__ w0, const float* __restrict__ w1,
    const float* __restrict__ w2, const float* __restrict__ w3,
    unsigned short* __restrict__ dstqkv, unsigned short* __restrict__ wt)
{
    __shared__ float t[32][33];
    const int tid = threadIdx.x;
    if (blockIdx.x < 12288) {
        const long gid = (long)blockIdx.x * 256 + tid;
        const int  tt  = (int)(gid >> 20);
        const long off = (gid & 1048575) << 2;
        const float* src = (tt == 0) ? q : (tt == 1) ? k : v;
        const float4 x = *(const float4*)(src + off);
        ushort4 o;
        o.x = f2b(x.x); o.y = f2b(x.y); o.z = f2b(x.z); o.w = f2b(x.w);
        *(ushort4*)(dstqkv + (long)tt * 4194304 + off) = o;
    } else {
        const int bb = blockIdx.x - 12288;      // 0..4095 = 32 x 32 x 4
        const int bx = bb & 31;                 // n-tile
        const int by = (bb >> 5) & 31;          // k-tile
        const int bz = bb >> 10;                // weight index
        const float* W = (bz == 0) ? w0 : (bz == 1) ? w1 : (bz == 2) ? w2 : w3;
        unsigned short* O = wt + (long)bz * 1048576;
        const int n0 = bx * 32, k0 = by * 32;
        const int tx = tid & 31, ty = tid >> 5;
        #pragma unroll
        for (int i = 0; i < 4; i++)
            t[ty + 8*i][tx] = W[(long)(k0 + ty + 8*i) * 1024 + n0 + tx];
        __syncthreads();
        #pragma unroll
        for (int i = 0; i < 4; i++)
            O[(long)(n0 + ty + 8*i) * 1024 + k0 + tx] = f2b(t[tx][ty + 8*i]);
    }
}

// ---------------- batched QKV projection GEMMs, PACKED-fragment epilogue ------
// BK=64, both-sides XOR-swizzled LDS (round 18).
// z=0 (Q), z=1 (K): addr = (R>>4)*16384 + (c>>5)*512 + (((c>>3)&3)*16+(R&15))*8 + (c&7)
// z=2 (V):          addr = (R>>5)*32768 + (c>>4)*512 + (((R>>3)&3)*16+(c&15))*8 + (R&7)
__global__ __launch_bounds__(256) void gemm3(
    const unsigned short* __restrict__ Abase,   // Xq | Xk | Xv (stride 4M elems)
    const unsigned short* __restrict__ WT,      // 3 weights (stride 1M elems)
    const float* __restrict__ bq, const float* __restrict__ bk, const float* __restrict__ bv,
    unsigned short* __restrict__ Cpk)           // Qf | Kf | Vf (stride 4M elems)
{
    __shared__ unsigned short As[128 * 64];
    __shared__ unsigned short Bs[128 * 64];
    const int z = blockIdx.z;
    const unsigned short* A  = Abase + (long)z * 4194304;
    const unsigned short* BT = WT    + (long)z * 1048576;
    unsigned short*       C  = Cpk   + (long)z * 4194304;
    const float* bias = (z == 0) ? bq : (z == 1) ? bk : bv;

    const int tid  = threadIdx.x;
    const int wave = tid >> 6, lane = tid & 63;
    const int l15  = lane & 15, l4 = lane >> 4;
    const int wr   = wave >> 1, wc = wave & 1;
    const int rowBase = blockIdx.x * 128;
    const int colBase = blockIdx.y * 128;
    const int K = 1024;

    f32x4 acc[4][4];
    #pragma unroll
    for (int m = 0; m < 4; m++)
        #pragma unroll
        for (int n = 0; n < 4; n++)
            acc[m][n] = (f32x4){0.f, 0.f, 0.f, 0.f};

    const int srow = wave * 32 + (lane >> 3);
    const int skk  = (((lane & 7) ^ ((lane >> 3) & 7))) * 8;
    const int fx   = (l15 & 7);

    for (int k0 = 0; k0 < K; k0 += 64) {
        #pragma unroll
        for (int u = 0; u < 4; u++) {
            GLL16(A  + (long)(rowBase + srow + u*8) * K + k0 + skk, As + (wave*32 + u*8) * 64);
            GLL16(BT + (long)(colBase + srow + u*8) * K + k0 + skk, Bs + (wave*32 + u*8) * 64);
        }
        __syncthreads();
        bf16x8 af[4][2], bfr[4][2];
        #pragma unroll
        for (int m = 0; m < 4; m++)
            #pragma unroll
            for (int kk = 0; kk < 2; kk++) {
                af[m][kk]  = *(const bf16x8*)(As + (wr*64 + m*16 + l15) * 64
                                               + (((kk*4 + l4) ^ fx) * 8));
                bfr[m][kk] = *(const bf16x8*)(Bs + (wc*64 + m*16 + l15) * 64
                                               + (((kk*4 + l4) ^ fx) * 8));
            }
        #pragma unroll
        for (int kk = 0; kk < 2; kk++)
            #pragma unroll
            for (int m = 0; m < 4; m++)
                #pragma unroll
                for (int n = 0; n < 4; n++)
                    acc[m][n] = __builtin_amdgcn_mfma_f32_16x16x32_bf16(af[m][kk], bfr[n][kk], acc[m][n], 0, 0, 0);
        __syncthreads();
    }

    #pragma unroll
    for (int m = 0; m < 4; m++) {
        const int R0 = rowBase + wr*64 + m*16 + l4*4;
        #pragma unroll
        for (int n = 0; n < 4; n++) {
            const int c = colBase + wc*64 + n*16 + l15;
            const float bv2 = bias[c];
            #pragma unroll
            for (int r = 0; r < 4; r++) {
                const int R = R0 + r;
                const float vv = acc[m][n][r] + bv2;
                long addr;
                if (z == 2)
                    addr = (long)(R >> 5) * 32768 + (c >> 4) * 512
                         + (((R >> 3) & 3) * 16 + (c & 15)) * 8 + (R & 7);
                else
                    addr = (long)(R >> 4) * 16384 + (c >> 5) * 512
                         + (((c >> 3) & 3) * 16 + (R & 15)) * 8 + (c & 7);
                C[addr] = f2b(vv);
            }
        }
    }
}

// ---------------- output GEMM with FUSED P0+P1 add ----------------------------
// C[M][N] = (P0+P1)[M][K](bf16) @ WT[N][K]^T + bias, f32 out.
// B-side: GLL16 swizzled staging (round 18). A-side: reg-staged — load both
// partials, add in f32, repack bf16, ds_write_b128 into the SAME swizzled
// layout Lds[r][c8] = Sum[r][c8 ^ (r&7)] so fragment reads are unchanged.
// Kills the addp kernel (24MB round-trip + launch).
__global__ __launch_bounds__(256) void gemm_fuseadd_f32(
    const unsigned short* __restrict__ P0,
    const unsigned short* __restrict__ P1,
    const unsigned short* __restrict__ BT,
    const float* __restrict__ bias,
    float* __restrict__ Cout)
{
    __shared__ unsigned short As[128 * 64];
    __shared__ unsigned short Bs[128 * 64];
    const int tid  = threadIdx.x;
    const int wave = tid >> 6, lane = tid & 63;
    const int l15  = lane & 15, l4 = lane >> 4;
    const int wr   = wave >> 1, wc = wave & 1;
    const int rowBase = blockIdx.x * 128;
    const int colBase = blockIdx.y * 128;
    const int N = 1024, K = 1024;

    f32x4 acc[4][4];
    #pragma unroll
    for (int m = 0; m < 4; m++)
        #pragma unroll
        for (int n = 0; n < 4; n++)
            acc[m][n] = (f32x4){0.f, 0.f, 0.f, 0.f};

    const int srow = wave * 32 + (lane >> 3);
    const int skk  = (((lane & 7) ^ ((lane >> 3) & 7))) * 8;
    const int fx   = (l15 & 7);
    const int ar   = tid >> 3;      // A-stage row within 32-row group
    const int ac8  = tid & 7;       // A-stage chunk

    for (int k0 = 0; k0 < K; k0 += 64) {
        #pragma unroll
        for (int u = 0; u < 4; u++)
            GLL16(BT + (long)(colBase + srow + u*8) * K + k0 + skk, Bs + (wave*32 + u*8) * 64);
        #pragma unroll
        for (int u = 0; u < 4; u++) {
            const int r   = u * 32 + ar;
            const int col = k0 + ((ac8 ^ (r & 7)) * 8);
            const long off = (long)(rowBase + r) * 1024 + col;
            const uint4 x0 = *(const uint4*)(P0 + off);
            const uint4 x1 = *(const uint4*)(P1 + off);
            const unsigned short* a = (const unsigned short*)&x0;
            const unsigned short* b = (const unsigned short*)&x1;
            unsigned short o[8];
            #pragma unroll
            for (int e = 0; e < 8; e++) o[e] = f2b(b2f(a[e]) + b2f(b[e]));
            *(uint4*)(As + r * 64 + ac8 * 8) = *(const uint4*)o;
        }
        __syncthreads();
        bf16x8 af[4][2], bfr[4][2];
        #pragma unroll
        for (int m = 0; m < 4; m++)
            #pragma unroll
            for (int kk = 0; kk < 2; kk++) {
                af[m][kk]  = *(const bf16x8*)(As + (wr*64 + m*16 + l15) * 64
                                               + (((kk*4 + l4) ^ fx) * 8));
                bfr[m][kk] = *(const bf16x8*)(Bs + (wc*64 + m*16 + l15) * 64
                                               + (((kk*4 + l4) ^ fx) * 8));
            }
        #pragma unroll
        for (int kk = 0; kk < 2; kk++)
            #pragma unroll
            for (int m = 0; m < 4; m++)
                #pragma unroll
                for (int n = 0; n < 4; n++)
                    acc[m][n] = __builtin_amdgcn_mfma_f32_16x16x32_bf16(af[m][kk], bfr[n][kk], acc[m][n], 0, 0, 0);
        __syncthreads();
    }

    #pragma unroll
    for (int m = 0; m < 4; m++) {
        const long row = rowBase + wr*64 + m*16 + l4*4;
        #pragma unroll
        for (int n = 0; n < 4; n++) {
            const long col = colBase + wc*64 + n*16 + l15;
            const float bv = bias[col];
            #pragma unroll
            for (int r = 0; r < 4; r++)
                Cout[(row + r) * N + col] = acc[m][n][r] + bv;
        }
    }
}

// ---------------- fused attention (round-13 structure, verified best) ---------
// Packed Qf/Kf/Vf loads (all coalesced lane*16B), 4 raw-barrier phases,
// S/P alias, 72KB LDS, 128-VGPR cap. + T5 setprio around MFMA clusters.
__global__ __launch_bounds__(512, 2) void attn_fused(
    const unsigned short* __restrict__ Qf_,  // packed [4][64][32][64][8]
    const unsigned short* __restrict__ Kf_,  // packed [4][64][32][64][8]
    const unsigned short* __restrict__ Vf_,  // packed [4][32][64][64][8]
    const int* __restrict__ mask,            // [1024*1024]
    unsigned short* __restrict__ P0,
    unsigned short* __restrict__ P1)
{
    __shared__ __align__(16) unsigned char smem[73728];
    float*         Se = (float*)smem;                 // [512 ij][18 f32] (72B rows)
    float*         So = (float*)(smem + 36864);       // [512 ij][18 f32]
    unsigned char* Pb = smem;                         // [16 h][32 i][72B], aliases Se

    const int tid = threadIdx.x, w = tid >> 6, lane = tid & 63;
    const int l15 = lane & 15, l4 = lane >> 4;
    const int h0  = 2 * w;
    const int sxor = h0 ^ (l4 << 2);

    // bijective XCD swizzle: 256 blocks -> 32 consecutive wg per XCD
    const int bid = blockIdx.x;
    const int wg  = (bid & 7) * 32 + (bid >> 3);
    const int b   = wg >> 6;
    const int jh  = (wg >> 5) & 1;
    const int i0  = (wg & 31) << 5;

    const unsigned short* Kfb = Kf_ + (long)b * 1048576;
    const unsigned short* Vfb = Vf_ + (long)b * 1048576;
    unsigned short* Pout = (jh == 0) ? P0 : P1;

    const int si = tid >> 4, sj = tid & 15;    // softmax thread -> (i row, j col)
    const int xorv = si & 12;                  // un-permutes the S h-slots
    const int mrow = (i0 + si) * 1024 + (jh << 9);

    // ---- Q fragments from packed Qf (coalesced, persistent)
    bf16x8 qf[2][2][2];   // [isub][hh][ks]
    #pragma unroll
    for (int is = 0; is < 2; is++)
        #pragma unroll
        for (int hh = 0; hh < 2; hh++)
            #pragma unroll
            for (int ks = 0; ks < 2; ks++)
                qf[is][hh][ks] = *(const bf16x8*)(Qf_ + (long)(b*64 + (i0 >> 4) + is) * 16384
                                                  + ((h0 + hh) * 2 + ks) * 512 + lane * 8);

#define LOAD_KF(JT) do { \
    _Pragma("unroll") \
    for (int t_ = 0; t_ < 2; t_++) \
        _Pragma("unroll") \
        for (int hh = 0; hh < 2; hh++) \
            _Pragma("unroll") \
            for (int ks = 0; ks < 2; ks++) \
                kf[t_][hh][ks] = *(const bf16x8*)(Kfb + ((JT) + t_) * 16384 \
                                                   + ((h0 + hh) * 2 + ks) * 512 + lane * 8); \
    } while(0)

#define LOAD_VF(JG) do { \
    _Pragma("unroll") \
    for (int hh = 0; hh < 2; hh++) \
        _Pragma("unroll") \
        for (int n = 0; n < 4; n++) \
            vf[hh][n] = *(const bf16x8*)(Vfb + (long)(JG) * 32768 \
                                           + ((h0 + hh) * 4 + n) * 512 + lane * 8); \
    } while(0)

    bf16x8 kf[2][2][2];   // [tile e/o][hh][ks]
    bf16x8 vf[2][4];      // [hh][n]
    LOAD_KF(jh*32);
    LOAD_VF(jh*16);

    f32x4 acc[2][2][4];   // [isub][hh][n]
    #pragma unroll
    for (int is = 0; is < 2; is++)
        #pragma unroll
        for (int hh = 0; hh < 2; hh++)
            #pragma unroll
            for (int n = 0; n < 4; n++)
                acc[is][hh][n] = (f32x4){0.f, 0.f, 0.f, 0.f};

    for (int g = 0; g < 16; ++g) {
        const int mke = mask[mrow + g * 32 + sj];
        const int mko = mask[mrow + g * 32 + 16 + sj];

        // ---- QK^T for both tiles (kf in regs)
        __builtin_amdgcn_s_setprio(1);
        #pragma unroll
        for (int t_ = 0; t_ < 2; t_++) {
            float* St = t_ ? So : Se;
            #pragma unroll
            for (int is = 0; is < 2; is++) {
                f32x4 sv0 = (f32x4){0.f,0.f,0.f,0.f}, sv1 = (f32x4){0.f,0.f,0.f,0.f};
                sv0 = __builtin_amdgcn_mfma_f32_16x16x32_bf16(qf[is][0][0], kf[t_][0][0], sv0, 0, 0, 0);
                sv0 = __builtin_amdgcn_mfma_f32_16x16x32_bf16(qf[is][0][1], kf[t_][0][1], sv0, 0, 0, 0);
                sv1 = __builtin_amdgcn_mfma_f32_16x16x32_bf16(qf[is][1][0], kf[t_][1][0], sv1, 0, 0, 0);
                sv1 = __builtin_amdgcn_mfma_f32_16x16x32_bf16(qf[is][1][1], kf[t_][1][1], sv1, 0, 0, 0);
                #pragma unroll
                for (int r = 0; r < 4; r++) {
                    const int ij = (is*16 + l4*4 + r) * 16 + l15;
                    f32x2 pr; pr[0] = sv0[r]; pr[1] = sv1[r];
                    *(f32x2*)(St + ij * 18 + sxor) = pr;
                }
            }
        }
        __builtin_amdgcn_s_setprio(0);
        LGKM0; BAR;                      // B1: S_e, S_o visible

        if (g < 15) LOAD_KF(jh*32 + (g + 1) * 2);   // coalesced refill for g+1

        // ---- softmax tile e (reads Se); packed result held across B2
        unsigned pe[8];
        {
            const float* sp = Se + tid * 18;
            float tv[16];
            #pragma unroll
            for (int q_ = 0; q_ < 8; q_++) {
                const f32x2 t2 = *(const f32x2*)(sp + q_ * 2);
                tv[q_*2] = t2[0]; tv[q_*2+1] = t2[1];
            }
            float Z = 0.f;
            #pragma unroll
            for (int h = 0; h < 16; h++) {
                float x = tv[h] * 0.18033688f;   // 0.125 * log2(e)
                if (mke == 0) x = -__builtin_inff();
                float e; asm("v_exp_f32 %0, %1" : "=v"(e) : "v"(x));
                tv[h] = e; Z += e;
            }
            float inv; asm("v_rcp_f32 %0, %1" : "=v"(inv) : "v"(Z));
            #pragma unroll
            for (int h = 0; h < 8; h++) {
                const unsigned lo = (__float_as_uint(tv[2*h]   * inv) + 0x8000u) >> 16;
                const unsigned hi = (__float_as_uint(tv[2*h+1] * inv) + 0x8000u) >> 16;
                pe[h] = lo | (hi << 16);
            }
        }
        BAR;                             // B2: ALL Se reads done -> P may overwrite
        #pragma unroll
        for (int h = 0; h < 16; h++) {
            const unsigned short pv = (unsigned short)((h & 1) ? (pe[h >> 1] >> 16) : pe[h >> 1]);
            *(unsigned short*)(Pb + (h ^ xorv) * 2304 + si * 72 + sj * 2) = pv;
        }

        // ---- softmax tile o (reads So: NOT aliased, safe during P writes)
        {
            const float* sp = So + tid * 18;
            float tv[16];
            #pragma unroll
            for (int q_ = 0; q_ < 8; q_++) {
                const f32x2 t2 = *(const f32x2*)(sp + q_ * 2);
                tv[q_*2] = t2[0]; tv[q_*2+1] = t2[1];
            }
            float Z = 0.f;
            #pragma unroll
            for (int h = 0; h < 16; h++) {
                float x = tv[h] * 0.18033688f;
                if (mko == 0) x = -__builtin_inff();
                float e; asm("v_exp_f32 %0, %1" : "=v"(e) : "v"(x));
                tv[h] = e; Z += e;
            }
            float inv; asm("v_rcp_f32 %0, %1" : "=v"(inv) : "v"(Z));
            #pragma unroll
            for (int h = 0; h < 16; h++) {
                const unsigned p16 = (__float_as_uint(tv[h] * inv) + 0x8000u) >> 16;
                *(unsigned short*)(Pb + (h ^ xorv) * 2304 + si * 72 + 32 + sj * 2) = (unsigned short)p16;
            }
        }
        LGKM0; BAR;                      // B3: P visible

        // ---- PV, full K=32 (P rows 72B -> paired b64 reads)
        {
            bf16x8 pa[2][2];
            #pragma unroll
            for (int is = 0; is < 2; is++)
                #pragma unroll
                for (int hh = 0; hh < 2; hh++) {
                    const unsigned char* pr = Pb + (h0 + hh) * 2304 + (is*16 + l15) * 72 + l4 * 16;
                    bf16x4 lo = *(const bf16x4*)(pr);
                    bf16x4 hi = *(const bf16x4*)(pr + 8);
                    pa[is][hh] = (bf16x8){lo[0],lo[1],lo[2],lo[3], hi[0],hi[1],hi[2],hi[3]};
                }
            __builtin_amdgcn_s_setprio(1);
            #pragma unroll
            for (int is = 0; is < 2; is++)
                #pragma unroll
                for (int hh = 0; hh < 2; hh++)
                    #pragma unroll
                    for (int n = 0; n < 4; n++)
                        acc[is][hh][n] = __builtin_amdgcn_mfma_f32_16x16x32_bf16(pa[is][hh], vf[hh][n], acc[is][hh][n], 0, 0, 0);
            __builtin_amdgcn_s_setprio(0);
        }
        if (g < 15) {
            LOAD_VF(jh*16 + g + 1);      // coalesced refill for g+1
            BAR;                         // B4: P reads done; next QK may write Se
        }
    }

    // ---- epilogue: bf16 partial
    #pragma unroll
    for (int is = 0; is < 2; is++)
        #pragma unroll
        for (int hh = 0; hh < 2; hh++)
            #pragma unroll
            for (int n = 0; n < 4; n++)
                #pragma unroll
                for (int r = 0; r < 4; r++) {
                    const long row = b * 1024 + i0 + is * 16 + l4 * 4 + r;
                    Pout[row * 1024 + (h0 + hh) * 64 + n * 16 + l15] = f2b(acc[is][hh][n][r]);
                }
#undef LOAD_KF
#undef LOAD_VF
}

extern "C" void kernel_launch(void* const* d_in, const int* in_sizes, int n_in,
                              void* d_out, int out_size, void* d_ws, size_t ws_size,
                              hipStream_t stream)
{
    const float* q    = (const float*)d_in[0];
    const float* k    = (const float*)d_in[1];
    const float* v    = (const float*)d_in[2];
    const int*   mask = (const int*)  d_in[3];
    const float* Wq   = (const float*)d_in[4];
    const float* bq   = (const float*)d_in[5];
    const float* Wk   = (const float*)d_in[6];
    const float* bk   = (const float*)d_in[7];
    const float* Wv   = (const float*)d_in[8];
    const float* bv   = (const float*)d_in[9];
    const float* Wo   = (const float*)d_in[10];
    const float* bo   = (const float*)d_in[11];

    unsigned short* ws = (unsigned short*)d_ws;
    const long MS = 1048576;
    unsigned short* WT  = ws;             // 4 transposed weights      [0,4M)
    unsigned short* Xq  = ws + 4*MS;      // bf16 query  -> later P1   [4M,8M)
    unsigned short* Xk  = ws + 8*MS;      // bf16 key    -> later P0   [8M,12M)
    unsigned short* Xv  = ws + 12*MS;     // bf16 value                [12M,16M)
    unsigned short* Qf  = ws + 16*MS;     // packed Q projection       [16M,20M)
    unsigned short* Kf  = ws + 20*MS;     // packed K projection       [20M,24M)
    unsigned short* Vf  = ws + 24*MS;     // packed V projection       [24M,28M)
    unsigned short* P0  = Xk;             // attn partial jh=0 (Xk dead after gemm3)
    unsigned short* P1  = Xq;             // attn partial jh=1 (Xq dead after gemm3)

    prep<<<16384, 256, 0, stream>>>(q, k, v, Wq, Wk, Wv, Wo, Xq, WT);
    gemm3<<<dim3(32, 8, 3), 256, 0, stream>>>(Xq, WT, bq, bk, bv, Qf);
    attn_fused<<<256, 512, 0, stream>>>(Qf, Kf, Vf, mask, P0, P1);
    gemm_fuseadd_f32<<<dim3(32, 8), 256, 0, stream>>>(P0, P1, WT + 3*MS, bo, (float*)d_out);
}